// Round 8
// baseline (441.162 us; speedup 1.0000x reference)
//
#include <hip/hip_runtime.h>

// Problem geometry (fixed by setup_inputs)
#define BB 32
#define DD 64
#define HWSZ 4096                  // H*W
#define KK 1024
#define NPIX (BB*HWSZ)             // 131072
#define NELEM (NPIX*DD)            // 8388608

// Output layout (concatenated float32)
#define IDX_OUT_OFF NELEM
#define LOSS_OFF (IDX_OUT_OFF + NPIX)

// Workspace layout (bytes)
#define WS_E2    0                        // 4 KB
#define WS_ET    (WS_E2 + 4096)           // 256 KB  eT[d][k]
#define WS_EBH   (WS_ET + DD*KK*4)        // 128 KB  B-frags hi
#define WS_EBL   (WS_EBH + KK*DD*2)       // 128 KB  B-frags lo
#define WS_IDX   (WS_EBL + KK*DD*2)       // 512 KB
#define WS_LIST  (WS_IDX + NPIX*4)        // 512 KB
#define WS_CNT   (WS_LIST + NPIX*4)       // 64 B
#define WS_PART  (WS_CNT + 64)            // 4 KB

// Ambiguity band: |fast-score - ref-fp32-score| <= ~1.5e-5 per score
// (ref's two magnitude-64 roundings 7.6e-6 + hi/lo-split residual ~6e-6);
// pairwise 3e-5. BAND=1.5e-4 = 5x margin (proven passing, rounds 6-7).
#define BAND 1.5e-4f

typedef __attribute__((ext_vector_type(8))) short short8v;
typedef __attribute__((ext_vector_type(4))) float float4v;

__device__ __forceinline__ unsigned short bf16_rne(float f) {
    unsigned u = __float_as_uint(f);
    u += 0x7fffu + ((u >> 16) & 1u);
    return (unsigned short)(u >> 16);
}
__device__ __forceinline__ float bf16_tof(unsigned short h) {
    return __uint_as_float(((unsigned)h) << 16);
}

// numpy-style fp32 sum of 64 squares (squares rounded separately; no FMA).
__device__ __forceinline__ float np_sumsq64(const float* a) {
#pragma clang fp contract(off)
    float r0=0.f,r1=0.f,r2=0.f,r3=0.f,r4=0.f,r5=0.f,r6=0.f,r7=0.f;
#pragma unroll
    for (int i = 0; i < 64; i += 8) {
        r0 += a[i+0]*a[i+0]; r1 += a[i+1]*a[i+1];
        r2 += a[i+2]*a[i+2]; r3 += a[i+3]*a[i+3];
        r4 += a[i+4]*a[i+4]; r5 += a[i+5]*a[i+5];
        r6 += a[i+6]*a[i+6]; r7 += a[i+7]*a[i+7];
    }
    return ((r0+r1)+(r2+r3))+((r4+r5)+(r6+r7));
}

// ---------------------------------------------------------------------------
__global__ __launch_bounds__(256) void vq_e2(const float* __restrict__ emb,
                                             float* __restrict__ e2) {
    int k = blockIdx.x * blockDim.x + threadIdx.x;
    float ek[DD];
    const float4* p = reinterpret_cast<const float4*>(emb + (size_t)k * DD);
#pragma unroll
    for (int q = 0; q < 16; ++q) {
        float4 v = p[q];
        ek[4*q+0]=v.x; ek[4*q+1]=v.y; ek[4*q+2]=v.z; ek[4*q+3]=v.w;
    }
    e2[k] = np_sumsq64(ek);
}

// ---------------------------------------------------------------------------
__global__ __launch_bounds__(256) void vq_transpose(const float* __restrict__ emb,
                                                    float* __restrict__ eT) {
    int i = blockIdx.x * blockDim.x + threadIdx.x;   // over 64*1024
    int d = i >> 10;
    int k = i & 1023;
    eT[i] = emb[(size_t)k * DD + d];
}

// ---------------------------------------------------------------------------
// B-fragments of the hi/lo bf16 split of emb^T (slot=ct*2+ks; see vq_main).
__global__ __launch_bounds__(256) void vq_bfrag(const float* __restrict__ emb,
                                                short* __restrict__ ebh,
                                                short* __restrict__ ebl) {
    int t    = blockIdx.x * 256 + threadIdx.x;   // 8192 = 128 slots * 64 lanes
    int l    = t & 63;
    int slot = t >> 6;
    int ct = slot >> 1, ks = slot & 1;
    int code  = ct*16 + (l & 15);
    int dbase = ks*32 + (l >> 4)*8;
    const float* ep = emb + (size_t)code*DD + dbase;
    short8v h, lo;
#pragma unroll
    for (int j = 0; j < 8; ++j) {
        float v = ep[j];
        unsigned short hh = bf16_rne(v);
        h[j]  = (short)hh;
        lo[j] = (short)bf16_rne(v - bf16_tof(hh));
    }
    ((short8v*)ebh)[t] = h;
    ((short8v*)ebl)[t] = lo;
}

// ---------------------------------------------------------------------------
// Main: 256 px/block x 1024 codes via bf16 MFMA (3-pass hi/lo), top-2 + band.
__global__ __launch_bounds__(256, 2) void vq_main(
        const float* __restrict__ z, const short* __restrict__ ebh,
        const short* __restrict__ ebl, const float* __restrict__ e2,
        int* __restrict__ idx, int* __restrict__ list, int* __restrict__ cnt) {
    __shared__ float zsh[DD * 256];      // 64 KB, [d][px]
    const int tid = threadIdx.x;
    const int w   = tid >> 6;
    const int l   = tid & 63;
    const int lr  = l & 15;
    const int lg  = l >> 4;
    const int b   = blockIdx.x >> 4;
    const int hw0 = (blockIdx.x & 15) * 256;
    const float* zb = z + (size_t)b*(DD*HWSZ) + hw0;

#pragma unroll 8
    for (int d = 0; d < DD; ++d)
        zsh[d * 256 + tid] = zb[(size_t)d * HWSZ + tid];
    __syncthreads();

    short8v ah[4][2], al[4][2];
#pragma unroll
    for (int rt = 0; rt < 4; ++rt) {
#pragma unroll
        for (int ks = 0; ks < 2; ++ks) {
            int px = w*64 + rt*16 + lr;
            int dbase = ks*32 + lg*8;
#pragma unroll
            for (int j = 0; j < 8; ++j) {
                float v = zsh[(dbase + j)*256 + px];
                unsigned short hh = bf16_rne(v);
                ah[rt][ks][j] = (short)hh;
                al[rt][ks][j] = (short)bf16_rne(v - bf16_tof(hh));
            }
        }
    }

    float best[4][4], best2[4][4];
    int   bib[4][4];
#pragma unroll
    for (int rt = 0; rt < 4; ++rt)
#pragma unroll
        for (int r = 0; r < 4; ++r) {
            best[rt][r] = 3.4e38f; best2[rt][r] = 3.4e38f; bib[rt][r] = 0;
        }

    const short8v* EBH = (const short8v*)ebh;
    const short8v* EBL = (const short8v*)ebl;

    short8v bh0 = EBH[l],  bh1 = EBH[64 + l];
    short8v bl0 = EBL[l],  bl1 = EBL[64 + l];
    float   e2c = e2[lr];

#pragma unroll 1
    for (int ct = 0; ct < 64; ++ct) {
        int ctn = (ct + 1) & 63;
        int s0  = ctn*128 + l;
        short8v nh0 = EBH[s0], nh1 = EBH[s0+64];
        short8v nl0 = EBL[s0], nl1 = EBL[s0+64];
        float   ne2 = e2[ctn*16 + lr];

        int kcol = ct*16 + lr;
#pragma unroll
        for (int rt = 0; rt < 4; ++rt) {
            float4v acc = {0.f, 0.f, 0.f, 0.f};
            acc = __builtin_amdgcn_mfma_f32_16x16x32_bf16(ah[rt][0], bh0, acc, 0,0,0);
            acc = __builtin_amdgcn_mfma_f32_16x16x32_bf16(ah[rt][1], bh1, acc, 0,0,0);
            acc = __builtin_amdgcn_mfma_f32_16x16x32_bf16(ah[rt][0], bl0, acc, 0,0,0);
            acc = __builtin_amdgcn_mfma_f32_16x16x32_bf16(ah[rt][1], bl1, acc, 0,0,0);
            acc = __builtin_amdgcn_mfma_f32_16x16x32_bf16(al[rt][0], bh0, acc, 0,0,0);
            acc = __builtin_amdgcn_mfma_f32_16x16x32_bf16(al[rt][1], bh1, acc, 0,0,0);
#pragma unroll
            for (int r = 0; r < 4; ++r) {
                float s = __builtin_fmaf(-2.f, acc[r], e2c);
                bool lt = s < best[rt][r];
                best2[rt][r] = lt ? best[rt][r] : fminf(best2[rt][r], s);
                best[rt][r]  = fminf(best[rt][r], s);
                bib[rt][r]   = lt ? kcol : bib[rt][r];
            }
        }
        bh0 = nh0; bh1 = nh1; bl0 = nl0; bl1 = nl1; e2c = ne2;
    }

#pragma unroll
    for (int rt = 0; rt < 4; ++rt) {
#pragma unroll
        for (int r = 0; r < 4; ++r) {
            float b1 = best[rt][r], b2 = best2[rt][r];
            int   bi = bib[rt][r];
#pragma unroll
            for (int m = 1; m < 16; m <<= 1) {
                float ob1 = __shfl_xor(b1, m, 64);
                float ob2 = __shfl_xor(b2, m, 64);
                int   obi = __shfl_xor(bi, m, 64);
                float nb2 = fminf(fmaxf(b1, ob1), fminf(b2, ob2));
                bool take = (ob1 < b1) || (ob1 == b1 && obi < bi);
                b1 = fminf(b1, ob1);
                bi = take ? obi : bi;
                b2 = nb2;
            }
            if (lr == 0) {
                int row = hw0 + w*64 + rt*16 + lg*4 + r;
                int n   = b*HWSZ + row;
                idx[n] = bi;
                if (b2 - b1 <= BAND) {
                    int p = atomicAdd(cnt, 1);
                    list[p] = n;
                }
            }
        }
    }
}

// ---------------------------------------------------------------------------
// Exact fp32 pass v3: ONE WAVE PER ROW. Lane l owns codes {l, l+64, .., l+960}
// (stride 64): per (d,g) the wave reads eT[d][g*64 .. g*64+63] = 256 B dense
// coalesced, L2-resident. Per-code chain bit-identical to the proven
// emulation: d-ascending fp32 FMA from 0; fl(z2+e2k); fmaf(-2,acc,A);
// global first-min via lexicographic (val, idx) wave reduce.
__global__ __launch_bounds__(256, 4) void vq_exact3(
        const float* __restrict__ z, const float* __restrict__ eT,
        const float* __restrict__ e2, const int* __restrict__ list,
        const int* __restrict__ cnt, int* __restrict__ idx) {
    __shared__ float zsh[4][64];
    const int l  = threadIdx.x & 63;
    const int ws = threadIdx.x >> 6;
    const int gw = (blockIdx.x << 2) | ws;   // global wave id
    const int nw = gridDim.x << 2;
    const int C  = *cnt;

    for (int i = gw; i < C; i += nw) {
        const int n  = list[i];
        const int bq = n >> 12, hw = n & 4095;
        const float* zp = z + (size_t)bq*(DD*HWSZ) + hw;

        zsh[ws][l] = zp[(size_t)l * HWSZ];       // 64 scattered loads in parallel
        asm volatile("s_waitcnt lgkmcnt(0) vmcnt(0)" ::: "memory"); // wave-sync

        float a[DD];
#pragma unroll
        for (int d = 0; d < DD; ++d) a[d] = zsh[ws][d];   // LDS broadcast reads
        const float z2 = np_sumsq64(a);

        float e2v[16];
#pragma unroll
        for (int g = 0; g < 16; ++g) e2v[g] = e2[g*64 + l];  // coalesced

        float acc[16];
#pragma unroll
        for (int g = 0; g < 16; ++g) acc[g] = 0.f;
#pragma unroll 4
        for (int d = 0; d < DD; ++d) {
            const float zd = a[d];
            const float* ed = eT + d*KK + l;
#pragma unroll
            for (int g = 0; g < 16; ++g)
                acc[g] = __builtin_fmaf(zd, ed[g*64], acc[g]);  // coalesced dword
        }

        float bestv = 3.4e38f; int bi = 0x7fffffff;
        {
#pragma clang fp contract(off)
#pragma unroll
            for (int g = 0; g < 16; ++g) {
                float A  = z2 + e2v[g];                      // fl(z2+e2k)
                float Bv = __builtin_fmaf(-2.f, acc[g], A);  // fl(A-2dot)
                int   k  = g*64 + l;                         // in-lane k asc
                if (Bv < bestv) { bestv = Bv; bi = k; }
            }
        }
#pragma unroll
        for (int m = 1; m < 64; m <<= 1) {                   // lex (val,idx) min
            float ov = __shfl_xor(bestv, m, 64);
            int   oi = __shfl_xor(bi, m, 64);
            if (ov < bestv || (ov == bestv && oi < bi)) { bestv = ov; bi = oi; }
        }
        if (l == 0) idx[n] = bi;
    }
}

// ---------------------------------------------------------------------------
__global__ __launch_bounds__(256) void vq_epilogue(
        const float* __restrict__ z, const float* __restrict__ emb,
        const int* __restrict__ idx, float* __restrict__ out,
        double* __restrict__ partial) {
    int n  = blockIdx.x * blockDim.x + threadIdx.x;
    int b  = n >> 12;
    int hw = n & 4095;
    const float* zp = z   + (size_t)b * (DD*HWSZ) + hw;
    float*       op = out + (size_t)b * (DD*HWSZ) + hw;
    int ki = idx[n];
    const float* ek = emb + (size_t)ki * DD;

    float lsum = 0.f;
#pragma unroll
    for (int d = 0; d < DD; ++d) {
        float e  = ek[d];
        float zv = zp[(size_t)d * HWSZ];
        op[(size_t)d * HWSZ] = e;            // z_q_st == z_q
        float df = e - zv;
        lsum = __builtin_fmaf(df, df, lsum);
    }
    out[IDX_OUT_OFF + n] = (float)ki;

    __shared__ double sred[256];
    sred[threadIdx.x] = (double)lsum;
    __syncthreads();
#pragma unroll
    for (int sdown = 128; sdown > 0; sdown >>= 1) {
        if (threadIdx.x < sdown) sred[threadIdx.x] += sred[threadIdx.x + sdown];
        __syncthreads();
    }
    if (threadIdx.x == 0) partial[blockIdx.x] = sred[0];
}

// ---------------------------------------------------------------------------
__global__ __launch_bounds__(256) void vq_finalize(
        const double* __restrict__ part, float* __restrict__ out) {
    __shared__ double sred[256];
    int t = threadIdx.x;
    sred[t] = part[t] + part[t + 256];       // 512 partials
    __syncthreads();
#pragma unroll
    for (int sdown = 128; sdown > 0; sdown >>= 1) {
        if (t < sdown) sred[t] += sred[t + sdown];
        __syncthreads();
    }
    if (t == 0) {
        double m = sred[0] / (double)NELEM;
        out[LOSS_OFF]     = (float)m;
        out[LOSS_OFF + 1] = (float)(0.25 * m);
    }
}

// ---------------------------------------------------------------------------
extern "C" void kernel_launch(void* const* d_in, const int* in_sizes, int n_in,
                              void* d_out, int out_size, void* d_ws, size_t ws_size,
                              hipStream_t stream) {
    const float* z   = (const float*)d_in[0];
    const float* emb = (const float*)d_in[1];
    float* out = (float*)d_out;
    char*  ws  = (char*)d_ws;

    float*  e2p  = (float*)(ws + WS_E2);
    float*  eT   = (float*)(ws + WS_ET);
    short*  ebh  = (short*)(ws + WS_EBH);
    short*  ebl  = (short*)(ws + WS_EBL);
    int*    idxp = (int*)(ws + WS_IDX);
    int*    lst  = (int*)(ws + WS_LIST);
    int*    cntp = (int*)(ws + WS_CNT);
    double* part = (double*)(ws + WS_PART);

    hipMemsetAsync(cntp, 0, 4, stream);
    vq_e2        <<<KK/256,      256, 0, stream>>>(emb, e2p);
    vq_transpose <<<(DD*KK)/256, 256, 0, stream>>>(emb, eT);
    vq_bfrag     <<<32,          256, 0, stream>>>(emb, ebh, ebl);
    vq_main      <<<NPIX/256,    256, 0, stream>>>(z, ebh, ebl, e2p, idxp, lst, cntp);
    vq_exact3    <<<1024,        256, 0, stream>>>(z, eT, e2p, lst, cntp, idxp);
    vq_epilogue  <<<NPIX/256,    256, 0, stream>>>(z, emb, idxp, out, part);
    vq_finalize  <<<1,           256, 0, stream>>>(part, out);
}

// Round 9
// 390.829 us; speedup vs baseline: 1.1288x; 1.1288x over previous
//
#include <hip/hip_runtime.h>

// Problem geometry (fixed by setup_inputs)
#define BB 32
#define DD 64
#define HWSZ 4096                  // H*W
#define KK 1024
#define NPIX (BB*HWSZ)             // 131072
#define NELEM (NPIX*DD)            // 8388608

// Output layout (concatenated float32)
#define IDX_OUT_OFF NELEM
#define LOSS_OFF (IDX_OUT_OFF + NPIX)

// Workspace layout (bytes)
#define WS_E2    0                        // 4 KB
#define WS_ET    (WS_E2 + 4096)           // 256 KB  eT[d][k]
#define WS_EBH   (WS_ET + DD*KK*4)        // 128 KB  B-frags hi
#define WS_EBL   (WS_EBH + KK*DD*2)       // 128 KB  B-frags lo
#define WS_IDX   (WS_EBL + KK*DD*2)       // 512 KB
#define WS_LIST  (WS_IDX + NPIX*4)        // 512 KB
#define WS_CNT   (WS_LIST + NPIX*4)       // 64 B
#define WS_PART  (WS_CNT + 64)            // 4 KB

// Ambiguity band: |fast-score - ref-fp32-score| <= ~1.5e-5 per score;
// pairwise 3e-5. BAND=1.5e-4 = 5x margin (proven passing, rounds 6-8).
#define BAND 1.5e-4f

typedef __attribute__((ext_vector_type(8))) short short8v;
typedef __attribute__((ext_vector_type(4))) float float4v;

__device__ __forceinline__ unsigned short bf16_rne(float f) {
    unsigned u = __float_as_uint(f);
    u += 0x7fffu + ((u >> 16) & 1u);
    return (unsigned short)(u >> 16);
}
__device__ __forceinline__ float bf16_tof(unsigned short h) {
    return __uint_as_float(((unsigned)h) << 16);
}

// numpy-style fp32 sum of 64 squares (squares rounded separately; no FMA).
__device__ __forceinline__ float np_sumsq64(const float* a) {
#pragma clang fp contract(off)
    float r0=0.f,r1=0.f,r2=0.f,r3=0.f,r4=0.f,r5=0.f,r6=0.f,r7=0.f;
#pragma unroll
    for (int i = 0; i < 64; i += 8) {
        r0 += a[i+0]*a[i+0]; r1 += a[i+1]*a[i+1];
        r2 += a[i+2]*a[i+2]; r3 += a[i+3]*a[i+3];
        r4 += a[i+4]*a[i+4]; r5 += a[i+5]*a[i+5];
        r6 += a[i+6]*a[i+6]; r7 += a[i+7]*a[i+7];
    }
    return ((r0+r1)+(r2+r3))+((r4+r5)+(r6+r7));
}

// Same semantics, reading from an LDS row (broadcast ds_reads, no a[64] regs).
__device__ __forceinline__ float np_sumsq64_lds(const float* sh) {
#pragma clang fp contract(off)
    float r0=0.f,r1=0.f,r2=0.f,r3=0.f,r4=0.f,r5=0.f,r6=0.f,r7=0.f;
#pragma unroll
    for (int i = 0; i < 64; i += 8) {
        float a0=sh[i+0],a1=sh[i+1],a2=sh[i+2],a3=sh[i+3];
        float a4=sh[i+4],a5=sh[i+5],a6=sh[i+6],a7=sh[i+7];
        r0 += a0*a0; r1 += a1*a1; r2 += a2*a2; r3 += a3*a3;
        r4 += a4*a4; r5 += a5*a5; r6 += a6*a6; r7 += a7*a7;
    }
    return ((r0+r1)+(r2+r3))+((r4+r5)+(r6+r7));
}

// ---------------------------------------------------------------------------
__global__ __launch_bounds__(256) void vq_e2(const float* __restrict__ emb,
                                             float* __restrict__ e2) {
    int k = blockIdx.x * blockDim.x + threadIdx.x;
    float ek[DD];
    const float4* p = reinterpret_cast<const float4*>(emb + (size_t)k * DD);
#pragma unroll
    for (int q = 0; q < 16; ++q) {
        float4 v = p[q];
        ek[4*q+0]=v.x; ek[4*q+1]=v.y; ek[4*q+2]=v.z; ek[4*q+3]=v.w;
    }
    e2[k] = np_sumsq64(ek);
}

// ---------------------------------------------------------------------------
__global__ __launch_bounds__(256) void vq_transpose(const float* __restrict__ emb,
                                                    float* __restrict__ eT) {
    int i = blockIdx.x * blockDim.x + threadIdx.x;   // over 64*1024
    int d = i >> 10;
    int k = i & 1023;
    eT[i] = emb[(size_t)k * DD + d];
}

// ---------------------------------------------------------------------------
// B-fragments of the hi/lo bf16 split of emb^T (slot=ct*2+ks; see vq_main).
__global__ __launch_bounds__(256) void vq_bfrag(const float* __restrict__ emb,
                                                short* __restrict__ ebh,
                                                short* __restrict__ ebl) {
    int t    = blockIdx.x * 256 + threadIdx.x;   // 8192 = 128 slots * 64 lanes
    int l    = t & 63;
    int slot = t >> 6;
    int ct = slot >> 1, ks = slot & 1;
    int code  = ct*16 + (l & 15);
    int dbase = ks*32 + (l >> 4)*8;
    const float* ep = emb + (size_t)code*DD + dbase;
    short8v h, lo;
#pragma unroll
    for (int j = 0; j < 8; ++j) {
        float v = ep[j];
        unsigned short hh = bf16_rne(v);
        h[j]  = (short)hh;
        lo[j] = (short)bf16_rne(v - bf16_tof(hh));
    }
    ((short8v*)ebh)[t] = h;
    ((short8v*)ebl)[t] = lo;
}

// ---------------------------------------------------------------------------
// Main: 256 px/block x 1024 codes via bf16 MFMA (3-pass hi/lo), top-2 + band.
__global__ __launch_bounds__(256, 2) void vq_main(
        const float* __restrict__ z, const short* __restrict__ ebh,
        const short* __restrict__ ebl, const float* __restrict__ e2,
        int* __restrict__ idx, int* __restrict__ list, int* __restrict__ cnt) {
    __shared__ float zsh[DD * 256];      // 64 KB, [d][px]
    const int tid = threadIdx.x;
    const int w   = tid >> 6;
    const int l   = tid & 63;
    const int lr  = l & 15;
    const int lg  = l >> 4;
    const int b   = blockIdx.x >> 4;
    const int hw0 = (blockIdx.x & 15) * 256;
    const float* zb = z + (size_t)b*(DD*HWSZ) + hw0;

#pragma unroll 8
    for (int d = 0; d < DD; ++d)
        zsh[d * 256 + tid] = zb[(size_t)d * HWSZ + tid];
    __syncthreads();

    short8v ah[4][2], al[4][2];
#pragma unroll
    for (int rt = 0; rt < 4; ++rt) {
#pragma unroll
        for (int ks = 0; ks < 2; ++ks) {
            int px = w*64 + rt*16 + lr;
            int dbase = ks*32 + lg*8;
#pragma unroll
            for (int j = 0; j < 8; ++j) {
                float v = zsh[(dbase + j)*256 + px];
                unsigned short hh = bf16_rne(v);
                ah[rt][ks][j] = (short)hh;
                al[rt][ks][j] = (short)bf16_rne(v - bf16_tof(hh));
            }
        }
    }

    float best[4][4], best2[4][4];
    int   bib[4][4];
#pragma unroll
    for (int rt = 0; rt < 4; ++rt)
#pragma unroll
        for (int r = 0; r < 4; ++r) {
            best[rt][r] = 3.4e38f; best2[rt][r] = 3.4e38f; bib[rt][r] = 0;
        }

    const short8v* EBH = (const short8v*)ebh;
    const short8v* EBL = (const short8v*)ebl;

    short8v bh0 = EBH[l],  bh1 = EBH[64 + l];
    short8v bl0 = EBL[l],  bl1 = EBL[64 + l];
    float   e2c = e2[lr];

#pragma unroll 1
    for (int ct = 0; ct < 64; ++ct) {
        int ctn = (ct + 1) & 63;
        int s0  = ctn*128 + l;
        short8v nh0 = EBH[s0], nh1 = EBH[s0+64];
        short8v nl0 = EBL[s0], nl1 = EBL[s0+64];
        float   ne2 = e2[ctn*16 + lr];

        int kcol = ct*16 + lr;
#pragma unroll
        for (int rt = 0; rt < 4; ++rt) {
            float4v acc = {0.f, 0.f, 0.f, 0.f};
            acc = __builtin_amdgcn_mfma_f32_16x16x32_bf16(ah[rt][0], bh0, acc, 0,0,0);
            acc = __builtin_amdgcn_mfma_f32_16x16x32_bf16(ah[rt][1], bh1, acc, 0,0,0);
            acc = __builtin_amdgcn_mfma_f32_16x16x32_bf16(ah[rt][0], bl0, acc, 0,0,0);
            acc = __builtin_amdgcn_mfma_f32_16x16x32_bf16(ah[rt][1], bl1, acc, 0,0,0);
            acc = __builtin_amdgcn_mfma_f32_16x16x32_bf16(al[rt][0], bh0, acc, 0,0,0);
            acc = __builtin_amdgcn_mfma_f32_16x16x32_bf16(al[rt][1], bh1, acc, 0,0,0);
#pragma unroll
            for (int r = 0; r < 4; ++r) {
                float s = __builtin_fmaf(-2.f, acc[r], e2c);
                bool lt = s < best[rt][r];
                best2[rt][r] = lt ? best[rt][r] : fminf(best2[rt][r], s);
                best[rt][r]  = fminf(best[rt][r], s);
                bib[rt][r]   = lt ? kcol : bib[rt][r];
            }
        }
        bh0 = nh0; bh1 = nh1; bl0 = nl0; bl1 = nl1; e2c = ne2;
    }

#pragma unroll
    for (int rt = 0; rt < 4; ++rt) {
#pragma unroll
        for (int r = 0; r < 4; ++r) {
            float b1 = best[rt][r], b2 = best2[rt][r];
            int   bi = bib[rt][r];
#pragma unroll
            for (int m = 1; m < 16; m <<= 1) {
                float ob1 = __shfl_xor(b1, m, 64);
                float ob2 = __shfl_xor(b2, m, 64);
                int   obi = __shfl_xor(bi, m, 64);
                float nb2 = fminf(fmaxf(b1, ob1), fminf(b2, ob2));
                bool take = (ob1 < b1) || (ob1 == b1 && obi < bi);
                b1 = fminf(b1, ob1);
                bi = take ? obi : bi;
                b2 = nb2;
            }
            if (lr == 0) {
                int row = hw0 + w*64 + rt*16 + lg*4 + r;
                int n   = b*HWSZ + row;
                idx[n] = bi;
                if (b2 - b1 <= BAND) {
                    int p = atomicAdd(cnt, 1);
                    list[p] = n;
                }
            }
        }
    }
}

// ---------------------------------------------------------------------------
// Exact fp32 pass v4: one wave per row, z LDS-resident (NO a[64] register
// array -> no scratch spills; round-8 lesson: VGPR=64 + spills = 266us).
// Lane l owns codes {l, l+64, ..., l+960}: per (d,g) the wave reads
// eT[d][g*64..g*64+63] = 256 B dense coalesced, L2-resident.
// Per-code chain bit-identical to the proven emulation.
__global__ __launch_bounds__(256, 4) void vq_exact4(
        const float* __restrict__ z, const float* __restrict__ eT,
        const float* __restrict__ e2, const int* __restrict__ list,
        const int* __restrict__ cnt, int* __restrict__ idx) {
    __shared__ float zsh[4][DD];
    const int l  = threadIdx.x & 63;
    const int ws = threadIdx.x >> 6;
    const int gw = (blockIdx.x << 2) | ws;   // global wave id
    const int nw = gridDim.x << 2;
    const int C  = *cnt;

    for (int i = gw; i < C; i += nw) {
        const int n  = list[i];
        const int bq = n >> 12, hw = n & 4095;
        const float* zp = z + (size_t)bq*(DD*HWSZ) + hw;

        zsh[ws][l] = zp[(size_t)l * HWSZ];       // 64 scattered loads, parallel
        asm volatile("s_waitcnt lgkmcnt(0) vmcnt(0)" ::: "memory"); // wave sync

        const float z2 = np_sumsq64_lds(zsh[ws]);

        float e2v[16];
#pragma unroll
        for (int g = 0; g < 16; ++g) e2v[g] = e2[g*64 + l];  // coalesced

        float acc[16];
#pragma unroll
        for (int g = 0; g < 16; ++g) acc[g] = 0.f;
#pragma unroll 2
        for (int d = 0; d < DD; ++d) {
            const float zd = zsh[ws][d];              // ds_read broadcast
            const float* ed = eT + d*KK + l;
#pragma unroll
            for (int g = 0; g < 16; ++g)
                acc[g] = __builtin_fmaf(zd, ed[g*64], acc[g]);  // coalesced
        }

        float bestv = 3.4e38f; int bi = 0x7fffffff;
        {
#pragma clang fp contract(off)
#pragma unroll
            for (int g = 0; g < 16; ++g) {
                float A  = z2 + e2v[g];                      // fl(z2+e2k)
                float Bv = __builtin_fmaf(-2.f, acc[g], A);  // fl(A-2dot)
                int   k  = g*64 + l;                         // in-lane k asc
                if (Bv < bestv) { bestv = Bv; bi = k; }
            }
        }
#pragma unroll
        for (int m = 1; m < 64; m <<= 1) {                   // lex (val,idx) min
            float ov = __shfl_xor(bestv, m, 64);
            int   oi = __shfl_xor(bi, m, 64);
            if (ov < bestv || (ov == bestv && oi < bi)) { bestv = ov; bi = oi; }
        }
        if (l == 0) idx[n] = bi;
    }
}

// ---------------------------------------------------------------------------
__global__ __launch_bounds__(256) void vq_epilogue(
        const float* __restrict__ z, const float* __restrict__ emb,
        const int* __restrict__ idx, float* __restrict__ out,
        double* __restrict__ partial) {
    int n  = blockIdx.x * blockDim.x + threadIdx.x;
    int b  = n >> 12;
    int hw = n & 4095;
    const float* zp = z   + (size_t)b * (DD*HWSZ) + hw;
    float*       op = out + (size_t)b * (DD*HWSZ) + hw;
    int ki = idx[n];
    const float* ek = emb + (size_t)ki * DD;

    float lsum = 0.f;
#pragma unroll
    for (int d = 0; d < DD; ++d) {
        float e  = ek[d];
        float zv = zp[(size_t)d * HWSZ];
        op[(size_t)d * HWSZ] = e;            // z_q_st == z_q
        float df = e - zv;
        lsum = __builtin_fmaf(df, df, lsum);
    }
    out[IDX_OUT_OFF + n] = (float)ki;

    __shared__ double sred[256];
    sred[threadIdx.x] = (double)lsum;
    __syncthreads();
#pragma unroll
    for (int sdown = 128; sdown > 0; sdown >>= 1) {
        if (threadIdx.x < sdown) sred[threadIdx.x] += sred[threadIdx.x + sdown];
        __syncthreads();
    }
    if (threadIdx.x == 0) partial[blockIdx.x] = sred[0];
}

// ---------------------------------------------------------------------------
__global__ __launch_bounds__(256) void vq_finalize(
        const double* __restrict__ part, float* __restrict__ out) {
    __shared__ double sred[256];
    int t = threadIdx.x;
    sred[t] = part[t] + part[t + 256];       // 512 partials
    __syncthreads();
#pragma unroll
    for (int sdown = 128; sdown > 0; sdown >>= 1) {
        if (t < sdown) sred[t] += sred[t + sdown];
        __syncthreads();
    }
    if (t == 0) {
        double m = sred[0] / (double)NELEM;
        out[LOSS_OFF]     = (float)m;
        out[LOSS_OFF + 1] = (float)(0.25 * m);
    }
}

// ---------------------------------------------------------------------------
extern "C" void kernel_launch(void* const* d_in, const int* in_sizes, int n_in,
                              void* d_out, int out_size, void* d_ws, size_t ws_size,
                              hipStream_t stream) {
    const float* z   = (const float*)d_in[0];
    const float* emb = (const float*)d_in[1];
    float* out = (float*)d_out;
    char*  ws  = (char*)d_ws;

    float*  e2p  = (float*)(ws + WS_E2);
    float*  eT   = (float*)(ws + WS_ET);
    short*  ebh  = (short*)(ws + WS_EBH);
    short*  ebl  = (short*)(ws + WS_EBL);
    int*    idxp = (int*)(ws + WS_IDX);
    int*    lst  = (int*)(ws + WS_LIST);
    int*    cntp = (int*)(ws + WS_CNT);
    double* part = (double*)(ws + WS_PART);

    hipMemsetAsync(cntp, 0, 4, stream);
    vq_e2        <<<KK/256,      256, 0, stream>>>(emb, e2p);
    vq_transpose <<<(DD*KK)/256, 256, 0, stream>>>(emb, eT);
    vq_bfrag     <<<32,          256, 0, stream>>>(emb, ebh, ebl);
    vq_main      <<<NPIX/256,    256, 0, stream>>>(z, ebh, ebl, e2p, idxp, lst, cntp);
    vq_exact4    <<<1024,        256, 0, stream>>>(z, eT, e2p, lst, cntp, idxp);
    vq_epilogue  <<<NPIX/256,    256, 0, stream>>>(z, emb, idxp, out, part);
    vq_finalize  <<<1,           256, 0, stream>>>(part, out);
}

// Round 10
// 342.818 us; speedup vs baseline: 1.2869x; 1.1400x over previous
//
#include <hip/hip_runtime.h>

// Problem geometry (fixed by setup_inputs)
#define BB 32
#define DD 64
#define HWSZ 4096                  // H*W
#define KK 1024
#define NPIX (BB*HWSZ)             // 131072
#define NELEM (NPIX*DD)            // 8388608

// Output layout (concatenated float32)
#define IDX_OUT_OFF NELEM
#define LOSS_OFF (IDX_OUT_OFF + NPIX)

// Workspace layout (bytes)
#define WS_E2    0                        // 4 KB
#define WS_ET    (WS_E2 + 4096)           // 256 KB  eT[d][k]
#define WS_EBH   (WS_ET + DD*KK*4)        // 128 KB  B-frags hi
#define WS_EBL   (WS_EBH + KK*DD*2)       // 128 KB  B-frags lo
#define WS_IDX   (WS_EBL + KK*DD*2)       // 512 KB
#define WS_LIST  (WS_IDX + NPIX*4)        // 512 KB
#define WS_CNT   (WS_LIST + NPIX*4)       // 64 B
#define WS_PART  (WS_CNT + 64)            // 4 KB
#define WS_ZROWS (WS_PART + 4096)         // packed z rows of flagged pixels

// Ambiguity band: |fast-score - ref-fp32-score| <= ~2e-5 pairwise;
// BAND = 1.5e-4 is ~7x margin (proven passing rounds 6-9).
#define BAND 1.5e-4f

typedef __attribute__((ext_vector_type(8))) short short8v;
typedef __attribute__((ext_vector_type(4))) float float4v;

__device__ __forceinline__ unsigned short bf16_rne(float f) {
    unsigned u = __float_as_uint(f);
    u += 0x7fffu + ((u >> 16) & 1u);
    return (unsigned short)(u >> 16);
}
__device__ __forceinline__ float bf16_tof(unsigned short h) {
    return __uint_as_float(((unsigned)h) << 16);
}

// numpy-style fp32 sum of 64 squares (squares rounded separately; no FMA).
__device__ __forceinline__ float np_sumsq64(const float* a) {
#pragma clang fp contract(off)
    float r0=0.f,r1=0.f,r2=0.f,r3=0.f,r4=0.f,r5=0.f,r6=0.f,r7=0.f;
#pragma unroll
    for (int i = 0; i < 64; i += 8) {
        r0 += a[i+0]*a[i+0]; r1 += a[i+1]*a[i+1];
        r2 += a[i+2]*a[i+2]; r3 += a[i+3]*a[i+3];
        r4 += a[i+4]*a[i+4]; r5 += a[i+5]*a[i+5];
        r6 += a[i+6]*a[i+6]; r7 += a[i+7]*a[i+7];
    }
    return ((r0+r1)+(r2+r3))+((r4+r5)+(r6+r7));
}

// Same bits, reading from an LDS row (broadcast ds_reads, no a[64] regs).
__device__ __forceinline__ float np_sumsq64_lds(const float* sh) {
#pragma clang fp contract(off)
    float r0=0.f,r1=0.f,r2=0.f,r3=0.f,r4=0.f,r5=0.f,r6=0.f,r7=0.f;
#pragma unroll
    for (int i = 0; i < 64; i += 8) {
        float a0=sh[i+0],a1=sh[i+1],a2=sh[i+2],a3=sh[i+3];
        float a4=sh[i+4],a5=sh[i+5],a6=sh[i+6],a7=sh[i+7];
        r0 += a0*a0; r1 += a1*a1; r2 += a2*a2; r3 += a3*a3;
        r4 += a4*a4; r5 += a5*a5; r6 += a6*a6; r7 += a7*a7;
    }
    return ((r0+r1)+(r2+r3))+((r4+r5)+(r6+r7));
}

// ---------------------------------------------------------------------------
__global__ __launch_bounds__(256) void vq_e2(const float* __restrict__ emb,
                                             float* __restrict__ e2) {
    int k = blockIdx.x * blockDim.x + threadIdx.x;
    float ek[DD];
    const float4* p = reinterpret_cast<const float4*>(emb + (size_t)k * DD);
#pragma unroll
    for (int q = 0; q < 16; ++q) {
        float4 v = p[q];
        ek[4*q+0]=v.x; ek[4*q+1]=v.y; ek[4*q+2]=v.z; ek[4*q+3]=v.w;
    }
    e2[k] = np_sumsq64(ek);
}

// ---------------------------------------------------------------------------
__global__ __launch_bounds__(256) void vq_transpose(const float* __restrict__ emb,
                                                    float* __restrict__ eT) {
    int i = blockIdx.x * blockDim.x + threadIdx.x;   // over 64*1024
    int d = i >> 10;
    int k = i & 1023;
    eT[i] = emb[(size_t)k * DD + d];
}

// ---------------------------------------------------------------------------
// B-fragments of the hi/lo bf16 split of emb^T (slot=ct*2+ks; see vq_main).
__global__ __launch_bounds__(256) void vq_bfrag(const float* __restrict__ emb,
                                                short* __restrict__ ebh,
                                                short* __restrict__ ebl) {
    int t    = blockIdx.x * 256 + threadIdx.x;   // 8192 = 128 slots * 64 lanes
    int l    = t & 63;
    int slot = t >> 6;
    int ct = slot >> 1, ks = slot & 1;
    int code  = ct*16 + (l & 15);
    int dbase = ks*32 + (l >> 4)*8;
    const float* ep = emb + (size_t)code*DD + dbase;
    short8v h, lo;
#pragma unroll
    for (int j = 0; j < 8; ++j) {
        float v = ep[j];
        unsigned short hh = bf16_rne(v);
        h[j]  = (short)hh;
        lo[j] = (short)bf16_rne(v - bf16_tof(hh));
    }
    ((short8v*)ebh)[t] = h;
    ((short8v*)ebl)[t] = lo;
}

// ---------------------------------------------------------------------------
// Main: 256 px/block x 1024 codes via bf16 MFMA (3-pass hi/lo), top-2 + band.
// Flagged rows: packed z copy into zrows[slot][64] (kills the exact-pass
// scattered gather that pinned rounds 6-9 at ~230us).
__global__ __launch_bounds__(256) void vq_main(
        const float* __restrict__ z, const short* __restrict__ ebh,
        const short* __restrict__ ebl, const float* __restrict__ e2,
        int* __restrict__ idx, int* __restrict__ list, int* __restrict__ cnt,
        float* __restrict__ zrows, int zcap) {
    __shared__ float zsh[DD * 256];      // 64 KB, [d][px]
    __shared__ int flpx[256];
    __shared__ int flslot[256];
    __shared__ int nfl;
    const int tid = threadIdx.x;
    const int w   = tid >> 6;
    const int l   = tid & 63;
    const int lr  = l & 15;
    const int lg  = l >> 4;
    const int b   = blockIdx.x >> 4;
    const int hw0 = (blockIdx.x & 15) * 256;
    const float* zb = z + (size_t)b*(DD*HWSZ) + hw0;

    if (tid == 0) nfl = 0;
#pragma unroll 8
    for (int d = 0; d < DD; ++d)
        zsh[d * 256 + tid] = zb[(size_t)d * HWSZ + tid];
    __syncthreads();

    short8v ah[4][2], al[4][2];
#pragma unroll
    for (int rt = 0; rt < 4; ++rt) {
#pragma unroll
        for (int ks = 0; ks < 2; ++ks) {
            int px = w*64 + rt*16 + lr;
            int dbase = ks*32 + lg*8;
#pragma unroll
            for (int j = 0; j < 8; ++j) {
                float v = zsh[(dbase + j)*256 + px];
                unsigned short hh = bf16_rne(v);
                ah[rt][ks][j] = (short)hh;
                al[rt][ks][j] = (short)bf16_rne(v - bf16_tof(hh));
            }
        }
    }

    float best[4][4], best2[4][4];
    int   bib[4][4];
#pragma unroll
    for (int rt = 0; rt < 4; ++rt)
#pragma unroll
        for (int r = 0; r < 4; ++r) {
            best[rt][r] = 3.4e38f; best2[rt][r] = 3.4e38f; bib[rt][r] = 0;
        }

    const short8v* EBH = (const short8v*)ebh;
    const short8v* EBL = (const short8v*)ebl;

#pragma unroll 1
    for (int ct = 0; ct < 64; ++ct) {
        int s0 = ct*128 + l;
        short8v bh0 = EBH[s0], bh1 = EBH[s0+64];
        short8v bl0 = EBL[s0], bl1 = EBL[s0+64];
        float   e2c = e2[ct*16 + lr];
        int kcol = ct*16 + lr;
#pragma unroll
        for (int rt = 0; rt < 4; ++rt) {
            float4v acc = {0.f, 0.f, 0.f, 0.f};
            acc = __builtin_amdgcn_mfma_f32_16x16x32_bf16(ah[rt][0], bh0, acc, 0,0,0);
            acc = __builtin_amdgcn_mfma_f32_16x16x32_bf16(ah[rt][1], bh1, acc, 0,0,0);
            acc = __builtin_amdgcn_mfma_f32_16x16x32_bf16(ah[rt][0], bl0, acc, 0,0,0);
            acc = __builtin_amdgcn_mfma_f32_16x16x32_bf16(ah[rt][1], bl1, acc, 0,0,0);
            acc = __builtin_amdgcn_mfma_f32_16x16x32_bf16(al[rt][0], bh0, acc, 0,0,0);
            acc = __builtin_amdgcn_mfma_f32_16x16x32_bf16(al[rt][1], bh1, acc, 0,0,0);
#pragma unroll
            for (int r = 0; r < 4; ++r) {
                float s = __builtin_fmaf(-2.f, acc[r], e2c);
                bool lt = s < best[rt][r];
                best2[rt][r] = lt ? best[rt][r] : fminf(best2[rt][r], s);
                best[rt][r]  = fminf(best[rt][r], s);
                bib[rt][r]   = lt ? kcol : bib[rt][r];
            }
        }
    }

#pragma unroll
    for (int rt = 0; rt < 4; ++rt) {
#pragma unroll
        for (int r = 0; r < 4; ++r) {
            float b1 = best[rt][r], b2 = best2[rt][r];
            int   bi = bib[rt][r];
#pragma unroll
            for (int m = 1; m < 16; m <<= 1) {
                float ob1 = __shfl_xor(b1, m, 64);
                float ob2 = __shfl_xor(b2, m, 64);
                int   obi = __shfl_xor(bi, m, 64);
                float nb2 = fminf(fmaxf(b1, ob1), fminf(b2, ob2));
                bool take = (ob1 < b1) || (ob1 == b1 && obi < bi);
                b1 = fminf(b1, ob1);
                bi = take ? obi : bi;
                b2 = nb2;
            }
            if (lr == 0) {
                int pxl = w*64 + rt*16 + lg*4 + r;         // local pixel
                int n   = b*HWSZ + hw0 + pxl;
                idx[n] = bi;
                if (b2 - b1 <= BAND) {
                    int p = atomicAdd(cnt, 1);
                    list[p] = n;
                    int j = atomicAdd(&nfl, 1);
                    flpx[j] = pxl;
                    flslot[j] = p;
                }
            }
        }
    }

    // block-cooperative packed z copy for flagged rows (coalesced stores)
    __syncthreads();
    int nf = nfl;
    for (int j0 = 0; j0 < nf; j0 += 4) {
        int jj = j0 + (tid >> 6);
        if (jj < nf) {
            int slot = flslot[jj];
            if (slot < zcap) {
                int d = tid & 63;
                zrows[(size_t)slot*64 + d] = zsh[d*256 + flpx[jj]];
            }
        }
    }
}

// ---------------------------------------------------------------------------
// Exact fp32 pass v5: one wave per 4 flagged rows; z from packed zrows
// (one coalesced 256 B load per row). Lane l owns codes {l, l+64, ..,
// l+960}; per (d,g) the wave reads eT[d][g*64..g*64+63] dense coalesced
// and feeds 4 FMAs. Per-code chain bit-identical to the proven emulation:
// d-ascending fp32 FMA from 0; fl(z2+e2k); fmaf(-2,acc,A); first-min.
__global__ __launch_bounds__(256, 4) void vq_exact5(
        const float* __restrict__ z, const float* __restrict__ eT,
        const float* __restrict__ e2, const float* __restrict__ zrows,
        const int* __restrict__ list, const int* __restrict__ cnt,
        int zcap, int* __restrict__ idx) {
    __shared__ float zsh[4][4][DD];      // [wave][row][d], 4 KB
    const int l  = threadIdx.x & 63;
    const int ws = threadIdx.x >> 6;
    const int gw = (blockIdx.x << 2) | ws;
    const int nw = gridDim.x << 2;
    const int C  = *cnt;

    float e2v[16];
#pragma unroll
    for (int g = 0; g < 16; ++g) e2v[g] = e2[g*64 + l];

    for (int i = gw; i*4 < C; i += nw) {
        const int base = i*4;
#pragma unroll
        for (int rr = 0; rr < 4; ++rr) {
            int ri = (base + rr < C) ? base + rr : C - 1;
            if (ri < zcap) {
                zsh[ws][rr][l] = zrows[(size_t)ri*64 + l];       // coalesced
            } else {                                             // fallback
                int n = list[ri];
                zsh[ws][rr][l] = z[(size_t)(n>>12)*(DD*HWSZ) + (n&4095)
                                   + (size_t)l*HWSZ];
            }
        }
        asm volatile("s_waitcnt lgkmcnt(0) vmcnt(0)" ::: "memory");

        float z2[4];
#pragma unroll
        for (int rr = 0; rr < 4; ++rr) z2[rr] = np_sumsq64_lds(zsh[ws][rr]);

        float acc[4][16];
#pragma unroll
        for (int rr = 0; rr < 4; ++rr)
#pragma unroll
            for (int g = 0; g < 16; ++g) acc[rr][g] = 0.f;

#pragma unroll 2
        for (int d = 0; d < DD; ++d) {
            float zd0 = zsh[ws][0][d], zd1 = zsh[ws][1][d];
            float zd2 = zsh[ws][2][d], zd3 = zsh[ws][3][d];
            const float* ed = eT + d*KK + l;
#pragma unroll
            for (int g = 0; g < 16; ++g) {
                float ev = ed[g*64];                  // coalesced, L2-resident
                acc[0][g] = __builtin_fmaf(zd0, ev, acc[0][g]);
                acc[1][g] = __builtin_fmaf(zd1, ev, acc[1][g]);
                acc[2][g] = __builtin_fmaf(zd2, ev, acc[2][g]);
                acc[3][g] = __builtin_fmaf(zd3, ev, acc[3][g]);
            }
        }

#pragma unroll
        for (int rr = 0; rr < 4; ++rr) {
            if (base + rr >= C) break;
            float bestv = 3.4e38f; int bi = 0x7fffffff;
            {
#pragma clang fp contract(off)
#pragma unroll
                for (int g = 0; g < 16; ++g) {
                    float A  = z2[rr] + e2v[g];                      // fl(z2+e2k)
                    float Bv = __builtin_fmaf(-2.f, acc[rr][g], A);  // fl(A-2dot)
                    int   k  = g*64 + l;
                    if (Bv < bestv) { bestv = Bv; bi = k; }
                }
            }
#pragma unroll
            for (int m = 1; m < 64; m <<= 1) {           // lex (val,idx) min
                float ov = __shfl_xor(bestv, m, 64);
                int   oi = __shfl_xor(bi, m, 64);
                if (ov < bestv || (ov == bestv && oi < bi)) { bestv = ov; bi = oi; }
            }
            if (l == 0) idx[list[base + rr]] = bi;
        }
    }
}

// ---------------------------------------------------------------------------
__global__ __launch_bounds__(256) void vq_epilogue(
        const float* __restrict__ z, const float* __restrict__ emb,
        const int* __restrict__ idx, float* __restrict__ out,
        double* __restrict__ partial) {
    int n  = blockIdx.x * blockDim.x + threadIdx.x;
    int b  = n >> 12;
    int hw = n & 4095;
    const float* zp = z   + (size_t)b * (DD*HWSZ) + hw;
    float*       op = out + (size_t)b * (DD*HWSZ) + hw;
    int ki = idx[n];
    const float* ek = emb + (size_t)ki * DD;

    float lsum = 0.f;
#pragma unroll
    for (int d = 0; d < DD; ++d) {
        float e  = ek[d];
        float zv = zp[(size_t)d * HWSZ];
        op[(size_t)d * HWSZ] = e;            // z_q_st == z_q
        float df = e - zv;
        lsum = __builtin_fmaf(df, df, lsum);
    }
    out[IDX_OUT_OFF + n] = (float)ki;

    __shared__ double sred[256];
    sred[threadIdx.x] = (double)lsum;
    __syncthreads();
#pragma unroll
    for (int sdown = 128; sdown > 0; sdown >>= 1) {
        if (threadIdx.x < sdown) sred[threadIdx.x] += sred[threadIdx.x + sdown];
        __syncthreads();
    }
    if (threadIdx.x == 0) partial[blockIdx.x] = sred[0];
}

// ---------------------------------------------------------------------------
__global__ __launch_bounds__(256) void vq_finalize(
        const double* __restrict__ part, float* __restrict__ out) {
    __shared__ double sred[256];
    int t = threadIdx.x;
    sred[t] = part[t] + part[t + 256];       // 512 partials
    __syncthreads();
#pragma unroll
    for (int sdown = 128; sdown > 0; sdown >>= 1) {
        if (t < sdown) sred[t] += sred[t + sdown];
        __syncthreads();
    }
    if (t == 0) {
        double m = sred[0] / (double)NELEM;
        out[LOSS_OFF]     = (float)m;
        out[LOSS_OFF + 1] = (float)(0.25 * m);
    }
}

// ---------------------------------------------------------------------------
extern "C" void kernel_launch(void* const* d_in, const int* in_sizes, int n_in,
                              void* d_out, int out_size, void* d_ws, size_t ws_size,
                              hipStream_t stream) {
    const float* z   = (const float*)d_in[0];
    const float* emb = (const float*)d_in[1];
    float* out = (float*)d_out;
    char*  ws  = (char*)d_ws;

    float*  e2p  = (float*)(ws + WS_E2);
    float*  eT   = (float*)(ws + WS_ET);
    short*  ebh  = (short*)(ws + WS_EBH);
    short*  ebl  = (short*)(ws + WS_EBL);
    int*    idxp = (int*)(ws + WS_IDX);
    int*    lst  = (int*)(ws + WS_LIST);
    int*    cntp = (int*)(ws + WS_CNT);
    double* part = (double*)(ws + WS_PART);
    float*  zrows = (float*)(ws + WS_ZROWS);

    // packed z-row capacity from whatever workspace remains (256 B per row)
    long long zrem = (long long)ws_size - (long long)WS_ZROWS;
    int zcap = zrem > 0 ? (int)(zrem / 256) : 0;
    if (zcap > NPIX) zcap = NPIX;

    hipMemsetAsync(cntp, 0, 4, stream);
    vq_e2        <<<KK/256,      256, 0, stream>>>(emb, e2p);
    vq_transpose <<<(DD*KK)/256, 256, 0, stream>>>(emb, eT);
    vq_bfrag     <<<32,          256, 0, stream>>>(emb, ebh, ebl);
    vq_main      <<<NPIX/256,    256, 0, stream>>>(z, ebh, ebl, e2p, idxp, lst,
                                                   cntp, zrows, zcap);
    vq_exact5    <<<512,         256, 0, stream>>>(z, eT, e2p, zrows, lst, cntp,
                                                   zcap, idxp);
    vq_epilogue  <<<NPIX/256,    256, 0, stream>>>(z, emb, idxp, out, part);
    vq_finalize  <<<1,           256, 0, stream>>>(part, out);
}

// Round 11
// 334.182 us; speedup vs baseline: 1.3201x; 1.0258x over previous
//
#include <hip/hip_runtime.h>

// Problem geometry (fixed by setup_inputs)
#define BB 32
#define DD 64
#define HWSZ 4096                  // H*W
#define KK 1024
#define NPIX (BB*HWSZ)             // 131072
#define NELEM (NPIX*DD)            // 8388608

// Output layout (concatenated float32)
#define IDX_OUT_OFF NELEM
#define LOSS_OFF (IDX_OUT_OFF + NPIX)

// Workspace layout (bytes)
#define WS_E2    0                        // 4 KB
#define WS_ET    (WS_E2 + 4096)           // 256 KB  eT[d][k]
#define WS_EBH   (WS_ET + DD*KK*4)        // 128 KB  B-frags hi
#define WS_EBL   (WS_EBH + KK*DD*2)       // 128 KB  B-frags lo
#define WS_IDX   (WS_EBL + KK*DD*2)       // 512 KB
#define WS_LIST  (WS_IDX + NPIX*4)        // 512 KB
#define WS_CNT   (WS_LIST + NPIX*4)       // 64 B
#define WS_PART  (WS_CNT + 64)            // 4 KB
#define WS_ZROWS (WS_PART + 4096)         // packed z rows of flagged pixels

// Ambiguity band: |fast-score - ref-fp32-score| <= ~2e-5 pairwise;
// BAND = 1.5e-4 is ~7x margin (proven passing rounds 6-10).
#define BAND 1.5e-4f

typedef __attribute__((ext_vector_type(8))) short short8v;
typedef __attribute__((ext_vector_type(4))) float float4v;

__device__ __forceinline__ unsigned short bf16_rne(float f) {
    unsigned u = __float_as_uint(f);
    u += 0x7fffu + ((u >> 16) & 1u);
    return (unsigned short)(u >> 16);
}
__device__ __forceinline__ float bf16_tof(unsigned short h) {
    return __uint_as_float(((unsigned)h) << 16);
}

// numpy-style fp32 sum of 64 squares (squares rounded separately; no FMA).
__device__ __forceinline__ float np_sumsq64(const float* a) {
#pragma clang fp contract(off)
    float r0=0.f,r1=0.f,r2=0.f,r3=0.f,r4=0.f,r5=0.f,r6=0.f,r7=0.f;
#pragma unroll
    for (int i = 0; i < 64; i += 8) {
        r0 += a[i+0]*a[i+0]; r1 += a[i+1]*a[i+1];
        r2 += a[i+2]*a[i+2]; r3 += a[i+3]*a[i+3];
        r4 += a[i+4]*a[i+4]; r5 += a[i+5]*a[i+5];
        r6 += a[i+6]*a[i+6]; r7 += a[i+7]*a[i+7];
    }
    return ((r0+r1)+(r2+r3))+((r4+r5)+(r6+r7));
}

// Same bits, reading from an LDS row (broadcast ds_reads, no a[64] regs).
__device__ __forceinline__ float np_sumsq64_lds(const float* sh) {
#pragma clang fp contract(off)
    float r0=0.f,r1=0.f,r2=0.f,r3=0.f,r4=0.f,r5=0.f,r6=0.f,r7=0.f;
#pragma unroll
    for (int i = 0; i < 64; i += 8) {
        float a0=sh[i+0],a1=sh[i+1],a2=sh[i+2],a3=sh[i+3];
        float a4=sh[i+4],a5=sh[i+5],a6=sh[i+6],a7=sh[i+7];
        r0 += a0*a0; r1 += a1*a1; r2 += a2*a2; r3 += a3*a3;
        r4 += a4*a4; r5 += a5*a5; r6 += a6*a6; r7 += a7*a7;
    }
    return ((r0+r1)+(r2+r3))+((r4+r5)+(r6+r7));
}

// ---------------------------------------------------------------------------
__global__ __launch_bounds__(256) void vq_e2(const float* __restrict__ emb,
                                             float* __restrict__ e2) {
    int k = blockIdx.x * blockDim.x + threadIdx.x;
    float ek[DD];
    const float4* p = reinterpret_cast<const float4*>(emb + (size_t)k * DD);
#pragma unroll
    for (int q = 0; q < 16; ++q) {
        float4 v = p[q];
        ek[4*q+0]=v.x; ek[4*q+1]=v.y; ek[4*q+2]=v.z; ek[4*q+3]=v.w;
    }
    e2[k] = np_sumsq64(ek);
}

// ---------------------------------------------------------------------------
__global__ __launch_bounds__(256) void vq_transpose(const float* __restrict__ emb,
                                                    float* __restrict__ eT) {
    int i = blockIdx.x * blockDim.x + threadIdx.x;   // over 64*1024
    int d = i >> 10;
    int k = i & 1023;
    eT[i] = emb[(size_t)k * DD + d];
}

// ---------------------------------------------------------------------------
// B-fragments of the hi/lo bf16 split of emb^T (slot=ct*2+ks; see vq_main).
__global__ __launch_bounds__(256) void vq_bfrag(const float* __restrict__ emb,
                                                short* __restrict__ ebh,
                                                short* __restrict__ ebl) {
    int t    = blockIdx.x * 256 + threadIdx.x;   // 8192 = 128 slots * 64 lanes
    int l    = t & 63;
    int slot = t >> 6;
    int ct = slot >> 1, ks = slot & 1;
    int code  = ct*16 + (l & 15);
    int dbase = ks*32 + (l >> 4)*8;
    const float* ep = emb + (size_t)code*DD + dbase;
    short8v h, lo;
#pragma unroll
    for (int j = 0; j < 8; ++j) {
        float v = ep[j];
        unsigned short hh = bf16_rne(v);
        h[j]  = (short)hh;
        lo[j] = (short)bf16_rne(v - bf16_tof(hh));
    }
    ((short8v*)ebh)[t] = h;
    ((short8v*)ebl)[t] = lo;
}

// ---------------------------------------------------------------------------
// Main: 256 px/block x 1024 codes via bf16 MFMA (3-pass hi/lo), top-2 + band.
// Flagged rows get a packed z copy into zrows[slot][64] (coalesced stores),
// so the exact pass never does a scattered gather.
__global__ __launch_bounds__(256) void vq_main(
        const float* __restrict__ z, const short* __restrict__ ebh,
        const short* __restrict__ ebl, const float* __restrict__ e2,
        int* __restrict__ idx, int* __restrict__ list, int* __restrict__ cnt,
        float* __restrict__ zrows, int zcap) {
    __shared__ float zsh[DD * 256];      // 64 KB, [d][px]
    __shared__ int flpx[256];
    __shared__ int flslot[256];
    __shared__ int nfl;
    const int tid = threadIdx.x;
    const int w   = tid >> 6;
    const int l   = tid & 63;
    const int lr  = l & 15;
    const int lg  = l >> 4;
    const int b   = blockIdx.x >> 4;
    const int hw0 = (blockIdx.x & 15) * 256;
    const float* zb = z + (size_t)b*(DD*HWSZ) + hw0;

    if (tid == 0) nfl = 0;
#pragma unroll 8
    for (int d = 0; d < DD; ++d)
        zsh[d * 256 + tid] = zb[(size_t)d * HWSZ + tid];
    __syncthreads();

    short8v ah[4][2], al[4][2];
#pragma unroll
    for (int rt = 0; rt < 4; ++rt) {
#pragma unroll
        for (int ks = 0; ks < 2; ++ks) {
            int px = w*64 + rt*16 + lr;
            int dbase = ks*32 + lg*8;
#pragma unroll
            for (int j = 0; j < 8; ++j) {
                float v = zsh[(dbase + j)*256 + px];
                unsigned short hh = bf16_rne(v);
                ah[rt][ks][j] = (short)hh;
                al[rt][ks][j] = (short)bf16_rne(v - bf16_tof(hh));
            }
        }
    }

    float best[4][4], best2[4][4];
    int   bib[4][4];
#pragma unroll
    for (int rt = 0; rt < 4; ++rt)
#pragma unroll
        for (int r = 0; r < 4; ++r) {
            best[rt][r] = 3.4e38f; best2[rt][r] = 3.4e38f; bib[rt][r] = 0;
        }

    const short8v* EBH = (const short8v*)ebh;
    const short8v* EBL = (const short8v*)ebl;

#pragma unroll 1
    for (int ct = 0; ct < 64; ++ct) {
        int s0 = ct*128 + l;
        short8v bh0 = EBH[s0], bh1 = EBH[s0+64];
        short8v bl0 = EBL[s0], bl1 = EBL[s0+64];
        float   e2c = e2[ct*16 + lr];
        int kcol = ct*16 + lr;
#pragma unroll
        for (int rt = 0; rt < 4; ++rt) {
            float4v acc = {0.f, 0.f, 0.f, 0.f};
            acc = __builtin_amdgcn_mfma_f32_16x16x32_bf16(ah[rt][0], bh0, acc, 0,0,0);
            acc = __builtin_amdgcn_mfma_f32_16x16x32_bf16(ah[rt][1], bh1, acc, 0,0,0);
            acc = __builtin_amdgcn_mfma_f32_16x16x32_bf16(ah[rt][0], bl0, acc, 0,0,0);
            acc = __builtin_amdgcn_mfma_f32_16x16x32_bf16(ah[rt][1], bl1, acc, 0,0,0);
            acc = __builtin_amdgcn_mfma_f32_16x16x32_bf16(al[rt][0], bh0, acc, 0,0,0);
            acc = __builtin_amdgcn_mfma_f32_16x16x32_bf16(al[rt][1], bh1, acc, 0,0,0);
#pragma unroll
            for (int r = 0; r < 4; ++r) {
                float s = __builtin_fmaf(-2.f, acc[r], e2c);
                bool lt = s < best[rt][r];
                best2[rt][r] = lt ? best[rt][r] : fminf(best2[rt][r], s);
                best[rt][r]  = fminf(best[rt][r], s);
                bib[rt][r]   = lt ? kcol : bib[rt][r];
            }
        }
    }

#pragma unroll
    for (int rt = 0; rt < 4; ++rt) {
#pragma unroll
        for (int r = 0; r < 4; ++r) {
            float b1 = best[rt][r], b2 = best2[rt][r];
            int   bi = bib[rt][r];
#pragma unroll
            for (int m = 1; m < 16; m <<= 1) {
                float ob1 = __shfl_xor(b1, m, 64);
                float ob2 = __shfl_xor(b2, m, 64);
                int   obi = __shfl_xor(bi, m, 64);
                float nb2 = fminf(fmaxf(b1, ob1), fminf(b2, ob2));
                bool take = (ob1 < b1) || (ob1 == b1 && obi < bi);
                b1 = fminf(b1, ob1);
                bi = take ? obi : bi;
                b2 = nb2;
            }
            if (lr == 0) {
                int pxl = w*64 + rt*16 + lg*4 + r;         // local pixel
                int n   = b*HWSZ + hw0 + pxl;
                idx[n] = bi;
                if (b2 - b1 <= BAND) {
                    int p = atomicAdd(cnt, 1);
                    list[p] = n;
                    int j = atomicAdd(&nfl, 1);
                    flpx[j] = pxl;
                    flslot[j] = p;
                }
            }
        }
    }

    // block-cooperative packed z copy for flagged rows (coalesced stores)
    __syncthreads();
    int nf = nfl;
    for (int j0 = 0; j0 < nf; j0 += 4) {
        int jj = j0 + (tid >> 6);
        if (jj < nf) {
            int slot = flslot[jj];
            if (slot < zcap) {
                int d = tid & 63;
                zrows[(size_t)slot*64 + d] = zsh[d*256 + flpx[jj]];
            }
        }
    }
}

// ---------------------------------------------------------------------------
// Exact fp32 pass v6 = exact4's spill-free 1-row-per-wave shape (VGPR=64,
// WRITE 224KB proven round 9) + packed zrows load (one coalesced 256 B line
// per row; kills the 26.5MB scatter that made exact4 220us).
// Lane l owns codes {l, l+64, .., l+960}; per (d,g) the wave reads
// eT[d][g*64..g*64+63] = 256 B dense coalesced, L2-resident.
// Per-code chain bit-identical to the proven emulation: d-ascending fp32
// FMA from 0; fl(z2+e2k); fmaf(-2,acc,A); lex (val,idx) first-min.
__global__ __launch_bounds__(256, 4) void vq_exact6(
        const float* __restrict__ z, const float* __restrict__ eT,
        const float* __restrict__ e2, const float* __restrict__ zrows,
        const int* __restrict__ list, const int* __restrict__ cnt,
        int zcap, int* __restrict__ idx) {
    __shared__ float zsh[4][DD];
    const int l  = threadIdx.x & 63;
    const int ws = threadIdx.x >> 6;
    const int gw = (blockIdx.x << 2) | ws;   // global wave id
    const int nw = gridDim.x << 2;
    const int C  = *cnt;

    float e2v[16];
#pragma unroll
    for (int g = 0; g < 16; ++g) e2v[g] = e2[g*64 + l];  // coalesced, hoisted

    for (int i = gw; i < C; i += nw) {
        if (i < zcap) {
            zsh[ws][l] = zrows[(size_t)i*64 + l];        // one 256 B line
        } else {                                         // capacity fallback
            int n = list[i];
            zsh[ws][l] = z[(size_t)(n>>12)*(DD*HWSZ) + (n&4095) + (size_t)l*HWSZ];
        }
        asm volatile("s_waitcnt lgkmcnt(0) vmcnt(0)" ::: "memory"); // wave sync

        const float z2 = np_sumsq64_lds(zsh[ws]);

        float acc[16];
#pragma unroll
        for (int g = 0; g < 16; ++g) acc[g] = 0.f;
#pragma unroll 2
        for (int d = 0; d < DD; ++d) {
            const float zd = zsh[ws][d];              // ds_read broadcast
            const float* ed = eT + d*KK + l;
#pragma unroll
            for (int g = 0; g < 16; ++g)
                acc[g] = __builtin_fmaf(zd, ed[g*64], acc[g]);  // coalesced
        }

        float bestv = 3.4e38f; int bi = 0x7fffffff;
        {
#pragma clang fp contract(off)
#pragma unroll
            for (int g = 0; g < 16; ++g) {
                float A  = z2 + e2v[g];                      // fl(z2+e2k)
                float Bv = __builtin_fmaf(-2.f, acc[g], A);  // fl(A-2dot)
                int   k  = g*64 + l;                         // in-lane k asc
                if (Bv < bestv) { bestv = Bv; bi = k; }
            }
        }
#pragma unroll
        for (int m = 1; m < 64; m <<= 1) {                   // lex (val,idx) min
            float ov = __shfl_xor(bestv, m, 64);
            int   oi = __shfl_xor(bi, m, 64);
            if (ov < bestv || (ov == bestv && oi < bi)) { bestv = ov; bi = oi; }
        }
        if (l == 0) idx[list[i]] = bi;
    }
}

// ---------------------------------------------------------------------------
__global__ __launch_bounds__(256) void vq_epilogue(
        const float* __restrict__ z, const float* __restrict__ emb,
        const int* __restrict__ idx, float* __restrict__ out,
        double* __restrict__ partial) {
    int n  = blockIdx.x * blockDim.x + threadIdx.x;
    int b  = n >> 12;
    int hw = n & 4095;
    const float* zp = z   + (size_t)b * (DD*HWSZ) + hw;
    float*       op = out + (size_t)b * (DD*HWSZ) + hw;
    int ki = idx[n];
    const float* ek = emb + (size_t)ki * DD;

    float lsum = 0.f;
#pragma unroll
    for (int d = 0; d < DD; ++d) {
        float e  = ek[d];
        float zv = zp[(size_t)d * HWSZ];
        op[(size_t)d * HWSZ] = e;            // z_q_st == z_q
        float df = e - zv;
        lsum = __builtin_fmaf(df, df, lsum);
    }
    out[IDX_OUT_OFF + n] = (float)ki;

    __shared__ double sred[256];
    sred[threadIdx.x] = (double)lsum;
    __syncthreads();
#pragma unroll
    for (int sdown = 128; sdown > 0; sdown >>= 1) {
        if (threadIdx.x < sdown) sred[threadIdx.x] += sred[threadIdx.x + sdown];
        __syncthreads();
    }
    if (threadIdx.x == 0) partial[blockIdx.x] = sred[0];
}

// ---------------------------------------------------------------------------
__global__ __launch_bounds__(256) void vq_finalize(
        const double* __restrict__ part, float* __restrict__ out) {
    __shared__ double sred[256];
    int t = threadIdx.x;
    sred[t] = part[t] + part[t + 256];       // 512 partials
    __syncthreads();
#pragma unroll
    for (int sdown = 128; sdown > 0; sdown >>= 1) {
        if (t < sdown) sred[t] += sred[t + sdown];
        __syncthreads();
    }
    if (t == 0) {
        double m = sred[0] / (double)NELEM;
        out[LOSS_OFF]     = (float)m;
        out[LOSS_OFF + 1] = (float)(0.25 * m);
    }
}

// ---------------------------------------------------------------------------
extern "C" void kernel_launch(void* const* d_in, const int* in_sizes, int n_in,
                              void* d_out, int out_size, void* d_ws, size_t ws_size,
                              hipStream_t stream) {
    const float* z   = (const float*)d_in[0];
    const float* emb = (const float*)d_in[1];
    float* out = (float*)d_out;
    char*  ws  = (char*)d_ws;

    float*  e2p  = (float*)(ws + WS_E2);
    float*  eT   = (float*)(ws + WS_ET);
    short*  ebh  = (short*)(ws + WS_EBH);
    short*  ebl  = (short*)(ws + WS_EBL);
    int*    idxp = (int*)(ws + WS_IDX);
    int*    lst  = (int*)(ws + WS_LIST);
    int*    cntp = (int*)(ws + WS_CNT);
    double* part = (double*)(ws + WS_PART);
    float*  zrows = (float*)(ws + WS_ZROWS);

    // packed z-row capacity from whatever workspace remains (256 B per row)
    long long zrem = (long long)ws_size - (long long)WS_ZROWS;
    int zcap = zrem > 0 ? (int)(zrem / 256) : 0;
    if (zcap > NPIX) zcap = NPIX;

    hipMemsetAsync(cntp, 0, 4, stream);
    vq_e2        <<<KK/256,      256, 0, stream>>>(emb, e2p);
    vq_transpose <<<(DD*KK)/256, 256, 0, stream>>>(emb, eT);
    vq_bfrag     <<<32,          256, 0, stream>>>(emb, ebh, ebl);
    vq_main      <<<NPIX/256,    256, 0, stream>>>(z, ebh, ebl, e2p, idxp, lst,
                                                   cntp, zrows, zcap);
    vq_exact6    <<<1024,        256, 0, stream>>>(z, eT, e2p, zrows, lst, cntp,
                                                   zcap, idxp);
    vq_epilogue  <<<NPIX/256,    256, 0, stream>>>(z, emb, idxp, out, part);
    vq_finalize  <<<1,           256, 0, stream>>>(part, out);
}

// Round 12
// 262.819 us; speedup vs baseline: 1.6786x; 1.2715x over previous
//
#include <hip/hip_runtime.h>

// Problem geometry (fixed by setup_inputs)
#define BB 32
#define DD 64
#define HWSZ 4096                  // H*W
#define KK 1024
#define NPIX (BB*HWSZ)             // 131072
#define NELEM (NPIX*DD)            // 8388608

// Output layout (concatenated float32)
#define IDX_OUT_OFF NELEM
#define LOSS_OFF (IDX_OUT_OFF + NPIX)

// Workspace layout (bytes)
#define WS_E2    0                        // 4 KB
#define WS_ET    (WS_E2 + 4096)           // 256 KB  eT[d][k]
#define WS_EBH   (WS_ET + DD*KK*4)        // 128 KB  B-frags hi
#define WS_EBL   (WS_EBH + KK*DD*2)       // 128 KB  B-frags lo
#define WS_IDX   (WS_EBL + KK*DD*2)       // 512 KB
#define WS_LIST  (WS_IDX + NPIX*4)        // 512 KB
#define WS_CNT   (WS_LIST + NPIX*4)       // 64 B
#define WS_PART  (WS_CNT + 64)            // 4 KB
#define WS_ZROWS (WS_PART + 4096)         // packed z rows (full-exact rows)

// Ambiguity band: |fast-score - ref-fp32-score| <= ~8.2e-6 per score
// (ref's two magnitude-64 roundings + MFMA split residual); pairwise
// ~1.7e-5. BAND = 1.5e-4 is ~9x margin (proven passing rounds 6-11).
#define BAND 1.5e-4f

typedef __attribute__((ext_vector_type(8))) short short8v;
typedef __attribute__((ext_vector_type(4))) float float4v;

__device__ __forceinline__ unsigned short bf16_rne(float f) {
    unsigned u = __float_as_uint(f);
    u += 0x7fffu + ((u >> 16) & 1u);
    return (unsigned short)(u >> 16);
}
__device__ __forceinline__ float bf16_tof(unsigned short h) {
    return __uint_as_float(((unsigned)h) << 16);
}

// numpy-style fp32 sum of 64 squares (squares rounded separately; no FMA).
__device__ __forceinline__ float np_sumsq64(const float* a) {
#pragma clang fp contract(off)
    float r0=0.f,r1=0.f,r2=0.f,r3=0.f,r4=0.f,r5=0.f,r6=0.f,r7=0.f;
#pragma unroll
    for (int i = 0; i < 64; i += 8) {
        r0 += a[i+0]*a[i+0]; r1 += a[i+1]*a[i+1];
        r2 += a[i+2]*a[i+2]; r3 += a[i+3]*a[i+3];
        r4 += a[i+4]*a[i+4]; r5 += a[i+5]*a[i+5];
        r6 += a[i+6]*a[i+6]; r7 += a[i+7]*a[i+7];
    }
    return ((r0+r1)+(r2+r3))+((r4+r5)+(r6+r7));
}

// Same bits, LDS source, sequential addresses.
__device__ __forceinline__ float np_sumsq64_lds(const float* sh) {
#pragma clang fp contract(off)
    float r0=0.f,r1=0.f,r2=0.f,r3=0.f,r4=0.f,r5=0.f,r6=0.f,r7=0.f;
#pragma unroll
    for (int i = 0; i < 64; i += 8) {
        float a0=sh[i+0],a1=sh[i+1],a2=sh[i+2],a3=sh[i+3];
        float a4=sh[i+4],a5=sh[i+5],a6=sh[i+6],a7=sh[i+7];
        r0 += a0*a0; r1 += a1*a1; r2 += a2*a2; r3 += a3*a3;
        r4 += a4*a4; r5 += a5*a5; r6 += a6*a6; r7 += a7*a7;
    }
    return ((r0+r1)+(r2+r3))+((r4+r5)+(r6+r7));
}

// Same bits, LDS source with element stride (column of [d][px] tile).
__device__ __forceinline__ float np_sumsq64_str(const float* sh, int stride) {
#pragma clang fp contract(off)
    float r0=0.f,r1=0.f,r2=0.f,r3=0.f,r4=0.f,r5=0.f,r6=0.f,r7=0.f;
#pragma unroll
    for (int i = 0; i < 64; i += 8) {
        float a0=sh[(i+0)*stride],a1=sh[(i+1)*stride];
        float a2=sh[(i+2)*stride],a3=sh[(i+3)*stride];
        float a4=sh[(i+4)*stride],a5=sh[(i+5)*stride];
        float a6=sh[(i+6)*stride],a7=sh[(i+7)*stride];
        r0 += a0*a0; r1 += a1*a1; r2 += a2*a2; r3 += a3*a3;
        r4 += a4*a4; r5 += a5*a5; r6 += a6*a6; r7 += a7*a7;
    }
    return ((r0+r1)+(r2+r3))+((r4+r5)+(r6+r7));
}

// ---------------------------------------------------------------------------
__global__ __launch_bounds__(256) void vq_e2(const float* __restrict__ emb,
                                             float* __restrict__ e2) {
    int k = blockIdx.x * blockDim.x + threadIdx.x;
    float ek[DD];
    const float4* p = reinterpret_cast<const float4*>(emb + (size_t)k * DD);
#pragma unroll
    for (int q = 0; q < 16; ++q) {
        float4 v = p[q];
        ek[4*q+0]=v.x; ek[4*q+1]=v.y; ek[4*q+2]=v.z; ek[4*q+3]=v.w;
    }
    e2[k] = np_sumsq64(ek);
}

// ---------------------------------------------------------------------------
__global__ __launch_bounds__(256) void vq_transpose(const float* __restrict__ emb,
                                                    float* __restrict__ eT) {
    int i = blockIdx.x * blockDim.x + threadIdx.x;   // over 64*1024
    int d = i >> 10;
    int k = i & 1023;
    eT[i] = emb[(size_t)k * DD + d];
}

// ---------------------------------------------------------------------------
// B-fragments of the hi/lo bf16 split of emb^T (slot=ct*2+ks; see vq_main).
__global__ __launch_bounds__(256) void vq_bfrag(const float* __restrict__ emb,
                                                short* __restrict__ ebh,
                                                short* __restrict__ ebl) {
    int t    = blockIdx.x * 256 + threadIdx.x;   // 8192 = 128 slots * 64 lanes
    int l    = t & 63;
    int slot = t >> 6;
    int ct = slot >> 1, ks = slot & 1;
    int code  = ct*16 + (l & 15);
    int dbase = ks*32 + (l >> 4)*8;
    const float* ep = emb + (size_t)code*DD + dbase;
    short8v h, lo;
#pragma unroll
    for (int j = 0; j < 8; ++j) {
        float v = ep[j];
        unsigned short hh = bf16_rne(v);
        h[j]  = (short)hh;
        lo[j] = (short)bf16_rne(v - bf16_tof(hh));
    }
    ((short8v*)ebh)[t] = h;
    ((short8v*)ebl)[t] = lo;
}

// ---------------------------------------------------------------------------
// Main: 256 px/block x 1024 codes via bf16 MFMA (3-pass hi/lo) with TOP-3
// tracking. Rows with b2-b1<=BAND but b3-b1>BAND have candidate set exactly
// {i1,i2}: resolved IN-KERNEL with 2 exact ref-semantics evaluations.
// Only rows with 3+ codes in band go to the full exact pass (rare).
__global__ __launch_bounds__(256) void vq_main(
        const float* __restrict__ z, const float* __restrict__ emb,
        const short* __restrict__ ebh, const short* __restrict__ ebl,
        const float* __restrict__ e2,
        int* __restrict__ idx, int* __restrict__ list, int* __restrict__ cnt,
        float* __restrict__ zrows, int zcap) {
    __shared__ float zsh[DD * 256];      // 64 KB, [d][px]
    __shared__ int flpx[256], flslot[256];
    __shared__ int q_px[256], q_k1[256], q_k2[256];
    __shared__ int nfl, n2c;
    const int tid = threadIdx.x;
    const int w   = tid >> 6;
    const int l   = tid & 63;
    const int lr  = l & 15;
    const int lg  = l >> 4;
    const int b   = blockIdx.x >> 4;
    const int hw0 = (blockIdx.x & 15) * 256;
    const float* zb = z + (size_t)b*(DD*HWSZ) + hw0;

    if (tid == 0) { nfl = 0; n2c = 0; }
#pragma unroll 8
    for (int d = 0; d < DD; ++d)
        zsh[d * 256 + tid] = zb[(size_t)d * HWSZ + tid];
    __syncthreads();

    short8v ah[4][2], al[4][2];
#pragma unroll
    for (int rt = 0; rt < 4; ++rt) {
#pragma unroll
        for (int ks = 0; ks < 2; ++ks) {
            int px = w*64 + rt*16 + lr;
            int dbase = ks*32 + lg*8;
#pragma unroll
            for (int j = 0; j < 8; ++j) {
                float v = zsh[(dbase + j)*256 + px];
                unsigned short hh = bf16_rne(v);
                ah[rt][ks][j] = (short)hh;
                al[rt][ks][j] = (short)bf16_rne(v - bf16_tof(hh));
            }
        }
    }

    float b1a[4][4], b2a[4][4], b3a[4][4];
    int   i1a[4][4], i2a[4][4];
#pragma unroll
    for (int rt = 0; rt < 4; ++rt)
#pragma unroll
        for (int r = 0; r < 4; ++r) {
            b1a[rt][r] = 3.4e38f; b2a[rt][r] = 3.4e38f; b3a[rt][r] = 3.4e38f;
            i1a[rt][r] = 0; i2a[rt][r] = 0;
        }

    const short8v* EBH = (const short8v*)ebh;
    const short8v* EBL = (const short8v*)ebl;

#pragma unroll 1
    for (int ct = 0; ct < 64; ++ct) {
        int s0 = ct*128 + l;
        short8v bh0 = EBH[s0], bh1 = EBH[s0+64];
        short8v bl0 = EBL[s0], bl1 = EBL[s0+64];
        float   e2c = e2[ct*16 + lr];
        int kcol = ct*16 + lr;
#pragma unroll
        for (int rt = 0; rt < 4; ++rt) {
            float4v acc = {0.f, 0.f, 0.f, 0.f};
            acc = __builtin_amdgcn_mfma_f32_16x16x32_bf16(ah[rt][0], bh0, acc, 0,0,0);
            acc = __builtin_amdgcn_mfma_f32_16x16x32_bf16(ah[rt][1], bh1, acc, 0,0,0);
            acc = __builtin_amdgcn_mfma_f32_16x16x32_bf16(ah[rt][0], bl0, acc, 0,0,0);
            acc = __builtin_amdgcn_mfma_f32_16x16x32_bf16(ah[rt][1], bl1, acc, 0,0,0);
            acc = __builtin_amdgcn_mfma_f32_16x16x32_bf16(al[rt][0], bh0, acc, 0,0,0);
            acc = __builtin_amdgcn_mfma_f32_16x16x32_bf16(al[rt][1], bh1, acc, 0,0,0);
#pragma unroll
            for (int r = 0; r < 4; ++r) {
                float s = __builtin_fmaf(-2.f, acc[r], e2c);
                bool lt1 = s < b1a[rt][r];
                bool lt2 = !lt1 && (s < b2a[rt][r]);
                bool lt3 = !lt1 && !lt2 && (s < b3a[rt][r]);
                b3a[rt][r] = (lt1 | lt2) ? b2a[rt][r] : (lt3 ? s : b3a[rt][r]);
                b2a[rt][r] = lt1 ? b1a[rt][r] : (lt2 ? s : b2a[rt][r]);
                i2a[rt][r] = lt1 ? i1a[rt][r] : (lt2 ? kcol : i2a[rt][r]);
                b1a[rt][r] = lt1 ? s : b1a[rt][r];
                i1a[rt][r] = lt1 ? kcol : i1a[rt][r];
            }
        }
    }

#pragma unroll
    for (int rt = 0; rt < 4; ++rt) {
#pragma unroll
        for (int r = 0; r < 4; ++r) {
            float b1 = b1a[rt][r], b2 = b2a[rt][r], b3 = b3a[rt][r];
            int   i1 = i1a[rt][r], i2 = i2a[rt][r];
#pragma unroll
            for (int m = 1; m < 16; m <<= 1) {       // sorted top-3 merge
                float o1 = __shfl_xor(b1, m, 64);
                float o2 = __shfl_xor(b2, m, 64);
                float o3 = __shfl_xor(b3, m, 64);
                int   oi1 = __shfl_xor(i1, m, 64);
                int   oi2 = __shfl_xor(i2, m, 64);
                bool take = (o1 < b1) || (o1 == b1 && oi1 < i1);
                float w1 = take?o1:b1;  int wi1 = take?oi1:i1;
                float l1 = take?b1:o1;  int li1 = take?i1:oi1;
                float w2 = take?o2:b2;  int wi2 = take?oi2:i2;
                float w3 = take?o3:b3;
                float l2 = take?b2:o2;
                bool t2 = (l1 < w2) || (l1 == w2 && li1 < wi2);
                float n2 = t2 ? l1 : w2;  int ni2 = t2 ? li1 : wi2;
                float n3 = fminf(fminf(fmaxf(w2, l1), w3), l2);
                b1 = w1; i1 = wi1; b2 = n2; i2 = ni2; b3 = n3;
            }
            if (lr == 0) {
                int pxl = w*64 + rt*16 + lg*4 + r;         // local pixel
                int n   = b*HWSZ + hw0 + pxl;
                idx[n] = i1;
                if (b2 - b1 <= BAND) {
                    if (b3 - b1 <= BAND) {                 // 3+ in band: full
                        int p = atomicAdd(cnt, 1);
                        list[p] = n;
                        int j = atomicAdd(&nfl, 1);
                        flpx[j] = pxl; flslot[j] = p;
                    } else {                               // exactly {i1,i2}
                        int j = atomicAdd(&n2c, 1);
                        q_px[j] = pxl; q_k1[j] = i1; q_k2[j] = i2;
                    }
                }
            }
        }
    }

    __syncthreads();
    // ---- 2-candidate exact resolve (ref fp32 bits), one thread per row ----
    if (tid < n2c) {
        int px = q_px[tid], k1 = q_k1[tid], k2 = q_k2[tid];
        float z2 = np_sumsq64_str(&zsh[px], 256);
        const float* ep1 = emb + (size_t)k1 * DD;
        const float* ep2 = emb + (size_t)k2 * DD;
        float s1 = 0.f, s2 = 0.f;
#pragma unroll
        for (int d = 0; d < DD; ++d) {                 // d-ascending chains
            float zd = zsh[d*256 + px];
            s1 = __builtin_fmaf(zd, ep1[d], s1);
            s2 = __builtin_fmaf(zd, ep2[d], s2);
        }
        float B1v, B2v;
        {
#pragma clang fp contract(off)
            float A1 = z2 + e2[k1]; B1v = __builtin_fmaf(-2.f, s1, A1);
            float A2 = z2 + e2[k2]; B2v = __builtin_fmaf(-2.f, s2, A2);
        }
        int win = (B1v < B2v) ? k1 : ((B2v < B1v) ? k2 : (k1 < k2 ? k1 : k2));
        idx[b*HWSZ + hw0 + px] = win;
    }

    // ---- packed z copy for full-exact rows (coalesced) ----
    __syncthreads();
    int nf = nfl;
    for (int j0 = 0; j0 < nf; j0 += 4) {
        int jj = j0 + (tid >> 6);
        if (jj < nf) {
            int slot = flslot[jj];
            if (slot < zcap) {
                int d = tid & 63;
                zrows[(size_t)slot*64 + d] = zsh[d*256 + flpx[jj]];
            }
        }
    }
}

// ---------------------------------------------------------------------------
// Full exact pass (rare rows: 3+ candidates in band). 1 row/wave, packed
// zrows source, spill-free (round-11 structure).
__global__ __launch_bounds__(256, 4) void vq_exact6(
        const float* __restrict__ z, const float* __restrict__ eT,
        const float* __restrict__ e2, const float* __restrict__ zrows,
        const int* __restrict__ list, const int* __restrict__ cnt,
        int zcap, int* __restrict__ idx) {
    __shared__ float zsh[4][DD];
    const int l  = threadIdx.x & 63;
    const int ws = threadIdx.x >> 6;
    const int gw = (blockIdx.x << 2) | ws;
    const int nw = gridDim.x << 2;
    const int C  = *cnt;

    float e2v[16];
#pragma unroll
    for (int g = 0; g < 16; ++g) e2v[g] = e2[g*64 + l];

    for (int i = gw; i < C; i += nw) {
        if (i < zcap) {
            zsh[ws][l] = zrows[(size_t)i*64 + l];
        } else {
            int n = list[i];
            zsh[ws][l] = z[(size_t)(n>>12)*(DD*HWSZ) + (n&4095) + (size_t)l*HWSZ];
        }
        asm volatile("s_waitcnt lgkmcnt(0) vmcnt(0)" ::: "memory");

        const float z2 = np_sumsq64_lds(zsh[ws]);

        float acc[16];
#pragma unroll
        for (int g = 0; g < 16; ++g) acc[g] = 0.f;
#pragma unroll 2
        for (int d = 0; d < DD; ++d) {
            const float zd = zsh[ws][d];
            const float* ed = eT + d*KK + l;
#pragma unroll
            for (int g = 0; g < 16; ++g)
                acc[g] = __builtin_fmaf(zd, ed[g*64], acc[g]);
        }

        float bestv = 3.4e38f; int bi = 0x7fffffff;
        {
#pragma clang fp contract(off)
#pragma unroll
            for (int g = 0; g < 16; ++g) {
                float A  = z2 + e2v[g];
                float Bv = __builtin_fmaf(-2.f, acc[g], A);
                int   k  = g*64 + l;
                if (Bv < bestv) { bestv = Bv; bi = k; }
            }
        }
#pragma unroll
        for (int m = 1; m < 64; m <<= 1) {
            float ov = __shfl_xor(bestv, m, 64);
            int   oi = __shfl_xor(bi, m, 64);
            if (ov < bestv || (ov == bestv && oi < bi)) { bestv = ov; bi = oi; }
        }
        if (l == 0) idx[list[i]] = bi;
    }
}

// ---------------------------------------------------------------------------
__global__ __launch_bounds__(256) void vq_epilogue(
        const float* __restrict__ z, const float* __restrict__ emb,
        const int* __restrict__ idx, float* __restrict__ out,
        double* __restrict__ partial) {
    int n  = blockIdx.x * blockDim.x + threadIdx.x;
    int b  = n >> 12;
    int hw = n & 4095;
    const float* zp = z   + (size_t)b * (DD*HWSZ) + hw;
    float*       op = out + (size_t)b * (DD*HWSZ) + hw;
    int ki = idx[n];
    const float* ek = emb + (size_t)ki * DD;

    float lsum = 0.f;
#pragma unroll
    for (int d = 0; d < DD; ++d) {
        float e  = ek[d];
        float zv = zp[(size_t)d * HWSZ];
        op[(size_t)d * HWSZ] = e;            // z_q_st == z_q
        float df = e - zv;
        lsum = __builtin_fmaf(df, df, lsum);
    }
    out[IDX_OUT_OFF + n] = (float)ki;

    __shared__ double sred[256];
    sred[threadIdx.x] = (double)lsum;
    __syncthreads();
#pragma unroll
    for (int sdown = 128; sdown > 0; sdown >>= 1) {
        if (threadIdx.x < sdown) sred[threadIdx.x] += sred[threadIdx.x + sdown];
        __syncthreads();
    }
    if (threadIdx.x == 0) partial[blockIdx.x] = sred[0];
}

// ---------------------------------------------------------------------------
__global__ __launch_bounds__(256) void vq_finalize(
        const double* __restrict__ part, float* __restrict__ out) {
    __shared__ double sred[256];
    int t = threadIdx.x;
    sred[t] = part[t] + part[t + 256];       // 512 partials
    __syncthreads();
#pragma unroll
    for (int sdown = 128; sdown > 0; sdown >>= 1) {
        if (t < sdown) sred[t] += sred[t + sdown];
        __syncthreads();
    }
    if (t == 0) {
        double m = sred[0] / (double)NELEM;
        out[LOSS_OFF]     = (float)m;
        out[LOSS_OFF + 1] = (float)(0.25 * m);
    }
}

// ---------------------------------------------------------------------------
extern "C" void kernel_launch(void* const* d_in, const int* in_sizes, int n_in,
                              void* d_out, int out_size, void* d_ws, size_t ws_size,
                              hipStream_t stream) {
    const float* z   = (const float*)d_in[0];
    const float* emb = (const float*)d_in[1];
    float* out = (float*)d_out;
    char*  ws  = (char*)d_ws;

    float*  e2p  = (float*)(ws + WS_E2);
    float*  eT   = (float*)(ws + WS_ET);
    short*  ebh  = (short*)(ws + WS_EBH);
    short*  ebl  = (short*)(ws + WS_EBL);
    int*    idxp = (int*)(ws + WS_IDX);
    int*    lst  = (int*)(ws + WS_LIST);
    int*    cntp = (int*)(ws + WS_CNT);
    double* part = (double*)(ws + WS_PART);
    float*  zrows = (float*)(ws + WS_ZROWS);

    long long zrem = (long long)ws_size - (long long)WS_ZROWS;
    int zcap = zrem > 0 ? (int)(zrem / 256) : 0;
    if (zcap > NPIX) zcap = NPIX;

    hipMemsetAsync(cntp, 0, 4, stream);
    vq_e2        <<<KK/256,      256, 0, stream>>>(emb, e2p);
    vq_transpose <<<(DD*KK)/256, 256, 0, stream>>>(emb, eT);
    vq_bfrag     <<<32,          256, 0, stream>>>(emb, ebh, ebl);
    vq_main      <<<NPIX/256,    256, 0, stream>>>(z, emb, ebh, ebl, e2p, idxp,
                                                   lst, cntp, zrows, zcap);
    vq_exact6    <<<1024,        256, 0, stream>>>(z, eT, e2p, zrows, lst, cntp,
                                                   zcap, idxp);
    vq_epilogue  <<<NPIX/256,    256, 0, stream>>>(z, emb, idxp, out, part);
    vq_finalize  <<<1,           256, 0, stream>>>(part, out);
}

// Round 14
// 157.034 us; speedup vs baseline: 2.8093x; 1.6736x over previous
//
#include <hip/hip_runtime.h>

// Problem geometry (fixed by setup_inputs)
#define BB 32
#define DD 64
#define HWSZ 4096                  // H*W
#define KK 1024
#define NPIX (BB*HWSZ)             // 131072
#define NELEM (NPIX*DD)            // 8388608

// Output layout (concatenated float32)
#define IDX_OUT_OFF NELEM
#define LOSS_OFF (IDX_OUT_OFF + NPIX)

// Workspace layout (bytes)
#define WS_E2    0                        // 4 KB
#define WS_ET    (WS_E2 + 4096)           // 256 KB  eT[d][k] (kept for compat)
#define WS_EBH   (WS_ET + DD*KK*4)        // 128 KB  B-frags hi
#define WS_EBL   (WS_EBH + KK*DD*2)       // 128 KB  B-frags lo
#define WS_IDX   (WS_EBL + KK*DD*2)       // 512 KB
#define WS_LIST  (WS_IDX + NPIX*4)        // 512 KB
#define WS_CNT   (WS_LIST + NPIX*4)       // 64 B
#define WS_PART  (WS_CNT + 64)            // 4 KB
#define WS_ZROWS (WS_PART + 4096)         // packed z rows (full-exact rows)

// Ambiguity band (proven rounds 6-12): pairwise fast-vs-ref error ~1.7e-5;
// BAND = 1.5e-4 is ~9x margin.
#define BAND 1.5e-4f

typedef __attribute__((ext_vector_type(8))) short short8v;
typedef __attribute__((ext_vector_type(4))) float float4v;

__device__ __forceinline__ unsigned short bf16_rne(float f) {
    unsigned u = __float_as_uint(f);
    u += 0x7fffu + ((u >> 16) & 1u);
    return (unsigned short)(u >> 16);
}
__device__ __forceinline__ float bf16_tof(unsigned short h) {
    return __uint_as_float(((unsigned)h) << 16);
}

// numpy-style fp32 sum of 64 squares (squares rounded separately; no FMA).
__device__ __forceinline__ float np_sumsq64(const float* a) {
#pragma clang fp contract(off)
    float r0=0.f,r1=0.f,r2=0.f,r3=0.f,r4=0.f,r5=0.f,r6=0.f,r7=0.f;
#pragma unroll
    for (int i = 0; i < 64; i += 8) {
        r0 += a[i+0]*a[i+0]; r1 += a[i+1]*a[i+1];
        r2 += a[i+2]*a[i+2]; r3 += a[i+3]*a[i+3];
        r4 += a[i+4]*a[i+4]; r5 += a[i+5]*a[i+5];
        r6 += a[i+6]*a[i+6]; r7 += a[i+7]*a[i+7];
    }
    return ((r0+r1)+(r2+r3))+((r4+r5)+(r6+r7));
}

// Same bits, LDS source, sequential addresses.
__device__ __forceinline__ float np_sumsq64_lds(const float* sh) {
#pragma clang fp contract(off)
    float r0=0.f,r1=0.f,r2=0.f,r3=0.f,r4=0.f,r5=0.f,r6=0.f,r7=0.f;
#pragma unroll
    for (int i = 0; i < 64; i += 8) {
        float a0=sh[i+0],a1=sh[i+1],a2=sh[i+2],a3=sh[i+3];
        float a4=sh[i+4],a5=sh[i+5],a6=sh[i+6],a7=sh[i+7];
        r0 += a0*a0; r1 += a1*a1; r2 += a2*a2; r3 += a3*a3;
        r4 += a4*a4; r5 += a5*a5; r6 += a6*a6; r7 += a7*a7;
    }
    return ((r0+r1)+(r2+r3))+((r4+r5)+(r6+r7));
}

// Same bits, LDS source with element stride (column of [d][px] tile).
__device__ __forceinline__ float np_sumsq64_str(const float* sh, int stride) {
#pragma clang fp contract(off)
    float r0=0.f,r1=0.f,r2=0.f,r3=0.f,r4=0.f,r5=0.f,r6=0.f,r7=0.f;
#pragma unroll
    for (int i = 0; i < 64; i += 8) {
        float a0=sh[(i+0)*stride],a1=sh[(i+1)*stride];
        float a2=sh[(i+2)*stride],a3=sh[(i+3)*stride];
        float a4=sh[(i+4)*stride],a5=sh[(i+5)*stride];
        float a6=sh[(i+6)*stride],a7=sh[(i+7)*stride];
        r0 += a0*a0; r1 += a1*a1; r2 += a2*a2; r3 += a3*a3;
        r4 += a4*a4; r5 += a5*a5; r6 += a6*a6; r7 += a7*a7;
    }
    return ((r0+r1)+(r2+r3))+((r4+r5)+(r6+r7));
}

// ---------------------------------------------------------------------------
__global__ __launch_bounds__(256) void vq_e2(const float* __restrict__ emb,
                                             float* __restrict__ e2) {
    int k = blockIdx.x * blockDim.x + threadIdx.x;
    float ek[DD];
    const float4* p = reinterpret_cast<const float4*>(emb + (size_t)k * DD);
#pragma unroll
    for (int q = 0; q < 16; ++q) {
        float4 v = p[q];
        ek[4*q+0]=v.x; ek[4*q+1]=v.y; ek[4*q+2]=v.z; ek[4*q+3]=v.w;
    }
    e2[k] = np_sumsq64(ek);
}

// ---------------------------------------------------------------------------
// B-fragments of the hi/lo bf16 split of emb^T (slot=ct*2+ks; see vq_main).
__global__ __launch_bounds__(256) void vq_bfrag(const float* __restrict__ emb,
                                                short* __restrict__ ebh,
                                                short* __restrict__ ebl) {
    int t    = blockIdx.x * 256 + threadIdx.x;   // 8192 = 128 slots * 64 lanes
    int l    = t & 63;
    int slot = t >> 6;
    int ct = slot >> 1, ks = slot & 1;
    int code  = ct*16 + (l & 15);
    int dbase = ks*32 + (l >> 4)*8;
    const float* ep = emb + (size_t)code*DD + dbase;
    short8v h, lo;
#pragma unroll
    for (int j = 0; j < 8; ++j) {
        float v = ep[j];
        unsigned short hh = bf16_rne(v);
        h[j]  = (short)hh;
        lo[j] = (short)bf16_rne(v - bf16_tof(hh));
    }
    ((short8v*)ebh)[t] = h;
    ((short8v*)ebl)[t] = lo;
}

// ---------------------------------------------------------------------------
// Main: 256 px/block x 1024 codes via bf16 MFMA (3-pass hi/lo), TOP-3 + band,
// in-kernel 2-candidate exact resolve, register DOUBLE-BUFFER of B-frags
// (round-12 counters: no-dbuf version stalls ~400cyc/ct on L2 latency).
__global__ __launch_bounds__(256) void vq_main(
        const float* __restrict__ z, const float* __restrict__ emb,
        const short* __restrict__ ebh, const short* __restrict__ ebl,
        const float* __restrict__ e2,
        int* __restrict__ idx, int* __restrict__ list, int* __restrict__ cnt,
        float* __restrict__ zrows, int zcap) {
    __shared__ float zsh[DD * 256];      // 64 KB, [d][px]
    __shared__ int flpx[256], flslot[256];
    __shared__ int q_px[256], q_k1[256], q_k2[256];
    __shared__ int nfl, n2c;
    const int tid = threadIdx.x;
    const int w   = tid >> 6;
    const int l   = tid & 63;
    const int lr  = l & 15;
    const int lg  = l >> 4;
    const int b   = blockIdx.x >> 4;
    const int hw0 = (blockIdx.x & 15) * 256;
    const float* zb = z + (size_t)b*(DD*HWSZ) + hw0;

    if (tid == 0) { nfl = 0; n2c = 0; }
#pragma unroll 8
    for (int d = 0; d < DD; ++d)
        zsh[d * 256 + tid] = zb[(size_t)d * HWSZ + tid];
    __syncthreads();

    short8v ah[4][2], al[4][2];
#pragma unroll
    for (int rt = 0; rt < 4; ++rt) {
#pragma unroll
        for (int ks = 0; ks < 2; ++ks) {
            int px = w*64 + rt*16 + lr;
            int dbase = ks*32 + lg*8;
#pragma unroll
            for (int j = 0; j < 8; ++j) {
                float v = zsh[(dbase + j)*256 + px];
                unsigned short hh = bf16_rne(v);
                ah[rt][ks][j] = (short)hh;
                al[rt][ks][j] = (short)bf16_rne(v - bf16_tof(hh));
            }
        }
    }

    float b1a[4][4], b2a[4][4], b3a[4][4];
    int   i1a[4][4], i2a[4][4];
#pragma unroll
    for (int rt = 0; rt < 4; ++rt)
#pragma unroll
        for (int r = 0; r < 4; ++r) {
            b1a[rt][r] = 3.4e38f; b2a[rt][r] = 3.4e38f; b3a[rt][r] = 3.4e38f;
            i1a[rt][r] = 0; i2a[rt][r] = 0;
        }

    const short8v* EBH = (const short8v*)ebh;
    const short8v* EBL = (const short8v*)ebl;

    // register double-buffer: frags + e2 for ct=0 loaded up front
    short8v bh0 = EBH[l],  bh1 = EBH[64 + l];
    short8v bl0 = EBL[l],  bl1 = EBL[64 + l];
    float   e2c = e2[lr];

#pragma unroll 1
    for (int ct = 0; ct < 64; ++ct) {
        int ctn = (ct + 1) & 63;             // wraps harmlessly on last iter
        int s0  = ctn*128 + l;
        short8v nh0 = EBH[s0], nh1 = EBH[s0+64];
        short8v nl0 = EBL[s0], nl1 = EBL[s0+64];
        float   ne2 = e2[ctn*16 + lr];

        int kcol = ct*16 + lr;
#pragma unroll
        for (int rt = 0; rt < 4; ++rt) {
            float4v acc = {0.f, 0.f, 0.f, 0.f};
            acc = __builtin_amdgcn_mfma_f32_16x16x32_bf16(ah[rt][0], bh0, acc, 0,0,0);
            acc = __builtin_amdgcn_mfma_f32_16x16x32_bf16(ah[rt][1], bh1, acc, 0,0,0);
            acc = __builtin_amdgcn_mfma_f32_16x16x32_bf16(ah[rt][0], bl0, acc, 0,0,0);
            acc = __builtin_amdgcn_mfma_f32_16x16x32_bf16(ah[rt][1], bl1, acc, 0,0,0);
            acc = __builtin_amdgcn_mfma_f32_16x16x32_bf16(al[rt][0], bh0, acc, 0,0,0);
            acc = __builtin_amdgcn_mfma_f32_16x16x32_bf16(al[rt][1], bh1, acc, 0,0,0);
#pragma unroll
            for (int r = 0; r < 4; ++r) {
                float s = __builtin_fmaf(-2.f, acc[r], e2c);
                bool lt1 = s < b1a[rt][r];
                bool lt2 = !lt1 && (s < b2a[rt][r]);
                bool lt3 = !lt1 && !lt2 && (s < b3a[rt][r]);
                b3a[rt][r] = (lt1 | lt2) ? b2a[rt][r] : (lt3 ? s : b3a[rt][r]);
                b2a[rt][r] = lt1 ? b1a[rt][r] : (lt2 ? s : b2a[rt][r]);
                i2a[rt][r] = lt1 ? i1a[rt][r] : (lt2 ? kcol : i2a[rt][r]);
                b1a[rt][r] = lt1 ? s : b1a[rt][r];
                i1a[rt][r] = lt1 ? kcol : i1a[rt][r];
            }
        }
        bh0 = nh0; bh1 = nh1; bl0 = nl0; bl1 = nl1; e2c = ne2;
    }

#pragma unroll
    for (int rt = 0; rt < 4; ++rt) {
#pragma unroll
        for (int r = 0; r < 4; ++r) {
            float b1 = b1a[rt][r], b2 = b2a[rt][r], b3 = b3a[rt][r];
            int   i1 = i1a[rt][r], i2 = i2a[rt][r];
#pragma unroll
            for (int m = 1; m < 16; m <<= 1) {       // sorted top-3 merge
                float o1 = __shfl_xor(b1, m, 64);
                float o2 = __shfl_xor(b2, m, 64);
                float o3 = __shfl_xor(b3, m, 64);
                int   oi1 = __shfl_xor(i1, m, 64);
                int   oi2 = __shfl_xor(i2, m, 64);
                bool take = (o1 < b1) || (o1 == b1 && oi1 < i1);
                float w1 = take?o1:b1;  int wi1 = take?oi1:i1;
                float l1 = take?b1:o1;  int li1 = take?i1:oi1;
                float w2 = take?o2:b2;  int wi2 = take?oi2:i2;
                float w3 = take?o3:b3;
                float l2 = take?b2:o2;
                bool t2 = (l1 < w2) || (l1 == w2 && li1 < wi2);
                float n2 = t2 ? l1 : w2;  int ni2 = t2 ? li1 : wi2;
                float n3 = fminf(fminf(fmaxf(w2, l1), w3), l2);
                b1 = w1; i1 = wi1; b2 = n2; i2 = ni2; b3 = n3;
            }
            if (lr == 0) {
                int pxl = w*64 + rt*16 + lg*4 + r;         // local pixel
                int n   = b*HWSZ + hw0 + pxl;
                idx[n] = i1;
                if (b2 - b1 <= BAND) {
                    if (b3 - b1 <= BAND) {                 // 3+ in band: full
                        int p = atomicAdd(cnt, 1);
                        list[p] = n;
                        int j = atomicAdd(&nfl, 1);
                        flpx[j] = pxl; flslot[j] = p;
                    } else {                               // exactly {i1,i2}
                        int j = atomicAdd(&n2c, 1);
                        q_px[j] = pxl; q_k1[j] = i1; q_k2[j] = i2;
                    }
                }
            }
        }
    }

    __syncthreads();
    // ---- 2-candidate exact resolve (ref fp32 bits), one thread per row ----
    if (tid < n2c) {
        int px = q_px[tid], k1 = q_k1[tid], k2 = q_k2[tid];
        float z2 = np_sumsq64_str(&zsh[px], 256);
        const float* ep1 = emb + (size_t)k1 * DD;
        const float* ep2 = emb + (size_t)k2 * DD;
        float s1 = 0.f, s2 = 0.f;
#pragma unroll
        for (int d = 0; d < DD; ++d) {                 // d-ascending chains
            float zd = zsh[d*256 + px];
            s1 = __builtin_fmaf(zd, ep1[d], s1);
            s2 = __builtin_fmaf(zd, ep2[d], s2);
        }
        float B1v, B2v;
        {
#pragma clang fp contract(off)
            float A1 = z2 + e2[k1]; B1v = __builtin_fmaf(-2.f, s1, A1);
            float A2 = z2 + e2[k2]; B2v = __builtin_fmaf(-2.f, s2, A2);
        }
        int win = (B1v < B2v) ? k1 : ((B2v < B1v) ? k2 : (k1 < k2 ? k1 : k2));
        idx[b*HWSZ + hw0 + px] = win;
    }

    // ---- packed z copy for full-exact rows (coalesced) ----
    __syncthreads();
    int nf = nfl;
    for (int j0 = 0; j0 < nf; j0 += 4) {
        int jj = j0 + (tid >> 6);
        if (jj < nf) {
            int slot = flslot[jj];
            if (slot < zcap) {
                int d = tid & 63;
                zrows[(size_t)slot*64 + d] = zsh[d*256 + flpx[jj]];
            }
        }
    }
}

// ---------------------------------------------------------------------------
// Full exact pass v7: ONE BLOCK (256 threads) per rare flagged row.
// Thread t evaluates codes {t, t+256, t+512, t+768} via emb row-major
// float4 loads -- 4 independent 64-deep d-ascending fp32 FMA chains
// (ref-bit-identical), in-thread k ascending keeps first-min; block-wide
// lex (val,idx) reduce. Kills the 1-wave-per-row latency straggler
// (round 12: single wave = ~120us regardless of C).
__global__ __launch_bounds__(256) void vq_exact7(
        const float* __restrict__ z, const float* __restrict__ emb,
        const float* __restrict__ e2, const float* __restrict__ zrows,
        const int* __restrict__ list, const int* __restrict__ cnt,
        int zcap, int* __restrict__ idx) {
    __shared__ float zsh[DD];
    __shared__ float rbv[256];
    __shared__ int   rbi[256];
    const int tid = threadIdx.x;
    const int C   = *cnt;

    for (int i = blockIdx.x; i < C; i += gridDim.x) {
        const int n = list[i];
        if (tid < 64) {
            if (i < zcap) {
                zsh[tid] = zrows[(size_t)i*64 + tid];      // coalesced line
            } else {
                zsh[tid] = z[(size_t)(n>>12)*(DD*HWSZ) + (n&4095)
                             + (size_t)tid*HWSZ];
            }
        }
        __syncthreads();

        const float z2 = np_sumsq64_lds(zsh);

        float bestv = 3.4e38f; int bi = 0x7fffffff;
#pragma unroll
        for (int c = 0; c < 4; ++c) {                  // k = tid + c*256, asc
            int k = c*256 + tid;
            const float4* ep = reinterpret_cast<const float4*>(emb + (size_t)k*DD);
            float s = 0.f;
#pragma unroll
            for (int q = 0; q < 16; ++q) {             // d-ascending chain
                float4 v = ep[q];
                float z0 = zsh[4*q+0], z1 = zsh[4*q+1];
                float z2v = zsh[4*q+2], z3 = zsh[4*q+3];
                s = __builtin_fmaf(z0, v.x, s);
                s = __builtin_fmaf(z1, v.y, s);
                s = __builtin_fmaf(z2v, v.z, s);
                s = __builtin_fmaf(z3, v.w, s);
            }
            float Bv;
            {
#pragma clang fp contract(off)
                float A = z2 + e2[k];
                Bv = __builtin_fmaf(-2.f, s, A);
            }
            if (Bv < bestv) { bestv = Bv; bi = k; }    // first-min (k asc)
        }

        rbv[tid] = bestv; rbi[tid] = bi;
        __syncthreads();
#pragma unroll
        for (int sdown = 128; sdown > 0; sdown >>= 1) {
            if (tid < sdown) {
                float ov = rbv[tid + sdown]; int oi = rbi[tid + sdown];
                if (ov < rbv[tid] || (ov == rbv[tid] && oi < rbi[tid])) {
                    rbv[tid] = ov; rbi[tid] = oi;
                }
            }
            __syncthreads();
        }
        if (tid == 0) idx[n] = rbi[0];
        __syncthreads();
    }
}

// ---------------------------------------------------------------------------
__global__ __launch_bounds__(256) void vq_epilogue(
        const float* __restrict__ z, const float* __restrict__ emb,
        const int* __restrict__ idx, float* __restrict__ out,
        double* __restrict__ partial) {
    int n  = blockIdx.x * blockDim.x + threadIdx.x;
    int b  = n >> 12;
    int hw = n & 4095;
    const float* zp = z   + (size_t)b * (DD*HWSZ) + hw;
    float*       op = out + (size_t)b * (DD*HWSZ) + hw;
    int ki = idx[n];
    const float* ek = emb + (size_t)ki * DD;

    float lsum = 0.f;
#pragma unroll
    for (int d = 0; d < DD; ++d) {
        float e  = ek[d];
        float zv = zp[(size_t)d * HWSZ];
        op[(size_t)d * HWSZ] = e;            // z_q_st == z_q
        float df = e - zv;
        lsum = __builtin_fmaf(df, df, lsum);
    }
    out[IDX_OUT_OFF + n] = (float)ki;

    __shared__ double sred[256];
    sred[threadIdx.x] = (double)lsum;
    __syncthreads();
#pragma unroll
    for (int sdown = 128; sdown > 0; sdown >>= 1) {
        if (threadIdx.x < sdown) sred[threadIdx.x] += sred[threadIdx.x + sdown];
        __syncthreads();
    }
    if (threadIdx.x == 0) partial[blockIdx.x] = sred[0];
}

// ---------------------------------------------------------------------------
__global__ __launch_bounds__(256) void vq_finalize(
        const double* __restrict__ part, float* __restrict__ out) {
    __shared__ double sred[256];
    int t = threadIdx.x;
    sred[t] = part[t] + part[t + 256];       // 512 partials
    __syncthreads();
#pragma unroll
    for (int sdown = 128; sdown > 0; sdown >>= 1) {
        if (t < sdown) sred[t] += sred[t + sdown];
        __syncthreads();
    }
    if (t == 0) {
        double m = sred[0] / (double)NELEM;
        out[LOSS_OFF]     = (float)m;
        out[LOSS_OFF + 1] = (float)(0.25 * m);
    }
}

// ---------------------------------------------------------------------------
extern "C" void kernel_launch(void* const* d_in, const int* in_sizes, int n_in,
                              void* d_out, int out_size, void* d_ws, size_t ws_size,
                              hipStream_t stream) {
    const float* z   = (const float*)d_in[0];
    const float* emb = (const float*)d_in[1];
    float* out = (float*)d_out;
    char*  ws  = (char*)d_ws;

    float*  e2p  = (float*)(ws + WS_E2);
    short*  ebh  = (short*)(ws + WS_EBH);
    short*  ebl  = (short*)(ws + WS_EBL);
    int*    idxp = (int*)(ws + WS_IDX);
    int*    lst  = (int*)(ws + WS_LIST);
    int*    cntp = (int*)(ws + WS_CNT);
    double* part = (double*)(ws + WS_PART);
    float*  zrows = (float*)(ws + WS_ZROWS);

    long long zrem = (long long)ws_size - (long long)WS_ZROWS;
    int zcap = zrem > 0 ? (int)(zrem / 256) : 0;
    if (zcap > NPIX) zcap = NPIX;

    hipMemsetAsync(cntp, 0, 4, stream);
    vq_e2       <<<KK/256,   256, 0, stream>>>(emb, e2p);
    vq_bfrag    <<<32,       256, 0, stream>>>(emb, ebh, ebl);
    vq_main     <<<NPIX/256, 256, 0, stream>>>(z, emb, ebh, ebl, e2p, idxp,
                                               lst, cntp, zrows, zcap);
    vq_exact7   <<<512,      256, 0, stream>>>(z, emb, e2p, zrows, lst, cntp,
                                               zcap, idxp);
    vq_epilogue <<<NPIX/256, 256, 0, stream>>>(z, emb, idxp, out, part);
    vq_finalize <<<1,        256, 0, stream>>>(part, out);
}

// Round 15
// 134.793 us; speedup vs baseline: 3.2729x; 1.1650x over previous
//
#include <hip/hip_runtime.h>

// Problem geometry (fixed by setup_inputs)
#define BB 32
#define DD 64
#define HWSZ 4096                  // H*W
#define KK 1024
#define NPIX (BB*HWSZ)             // 131072
#define NELEM (NPIX*DD)            // 8388608

// Output layout (concatenated float32)
#define IDX_OUT_OFF NELEM
#define LOSS_OFF (IDX_OUT_OFF + NPIX)

// Workspace layout (bytes)
#define WS_E2    0                        // 4 KB
#define WS_EBH   4096                     // 128 KB  B-frags hi
#define WS_EBL   (WS_EBH + KK*DD*2)       // 128 KB  B-frags lo
#define WS_IDX   (WS_EBL + KK*DD*2)       // 512 KB
#define WS_LIST  (WS_IDX + NPIX*4)        // 512 KB
#define WS_CNT   (WS_LIST + NPIX*4)       // 64 B: cnt@+0, loss-delta double@+8
#define WS_PART  (WS_CNT + 64)            // 8 KB (1024 doubles)
#define WS_ZROWS (WS_PART + 8192)         // packed z rows (full-exact rows)

// px per block (round-15: halved to double occupancy; zsh 32KB -> 4 blk/CU)
#define PXB 128
#define ZSTR 129                   // zsh row stride (pad: 4-way bank -> free 2-way)

// Ambiguity band (proven rounds 6-14): pairwise fast-vs-ref error ~1.7e-5;
// BAND = 1.5e-4 is ~9x margin.
#define BAND 1.5e-4f

typedef __attribute__((ext_vector_type(8))) short short8v;
typedef __attribute__((ext_vector_type(4))) float float4v;

__device__ __forceinline__ unsigned short bf16_rne(float f) {
    unsigned u = __float_as_uint(f);
    u += 0x7fffu + ((u >> 16) & 1u);
    return (unsigned short)(u >> 16);
}
__device__ __forceinline__ float bf16_tof(unsigned short h) {
    return __uint_as_float(((unsigned)h) << 16);
}

// numpy-style fp32 sum of 64 squares (squares rounded separately; no FMA).
__device__ __forceinline__ float np_sumsq64(const float* a) {
#pragma clang fp contract(off)
    float r0=0.f,r1=0.f,r2=0.f,r3=0.f,r4=0.f,r5=0.f,r6=0.f,r7=0.f;
#pragma unroll
    for (int i = 0; i < 64; i += 8) {
        r0 += a[i+0]*a[i+0]; r1 += a[i+1]*a[i+1];
        r2 += a[i+2]*a[i+2]; r3 += a[i+3]*a[i+3];
        r4 += a[i+4]*a[i+4]; r5 += a[i+5]*a[i+5];
        r6 += a[i+6]*a[i+6]; r7 += a[i+7]*a[i+7];
    }
    return ((r0+r1)+(r2+r3))+((r4+r5)+(r6+r7));
}

// Same bits, LDS source, sequential addresses.
__device__ __forceinline__ float np_sumsq64_lds(const float* sh) {
#pragma clang fp contract(off)
    float r0=0.f,r1=0.f,r2=0.f,r3=0.f,r4=0.f,r5=0.f,r6=0.f,r7=0.f;
#pragma unroll
    for (int i = 0; i < 64; i += 8) {
        float a0=sh[i+0],a1=sh[i+1],a2=sh[i+2],a3=sh[i+3];
        float a4=sh[i+4],a5=sh[i+5],a6=sh[i+6],a7=sh[i+7];
        r0 += a0*a0; r1 += a1*a1; r2 += a2*a2; r3 += a3*a3;
        r4 += a4*a4; r5 += a5*a5; r6 += a6*a6; r7 += a7*a7;
    }
    return ((r0+r1)+(r2+r3))+((r4+r5)+(r6+r7));
}

// Same bits, LDS source with element stride (column of [d][px] tile).
__device__ __forceinline__ float np_sumsq64_str(const float* sh, int stride) {
#pragma clang fp contract(off)
    float r0=0.f,r1=0.f,r2=0.f,r3=0.f,r4=0.f,r5=0.f,r6=0.f,r7=0.f;
#pragma unroll
    for (int i = 0; i < 64; i += 8) {
        float a0=sh[(i+0)*stride],a1=sh[(i+1)*stride];
        float a2=sh[(i+2)*stride],a3=sh[(i+3)*stride];
        float a4=sh[(i+4)*stride],a5=sh[(i+5)*stride];
        float a6=sh[(i+6)*stride],a7=sh[(i+7)*stride];
        r0 += a0*a0; r1 += a1*a1; r2 += a2*a2; r3 += a3*a3;
        r4 += a4*a4; r5 += a5*a5; r6 += a6*a6; r7 += a7*a7;
    }
    return ((r0+r1)+(r2+r3))+((r4+r5)+(r6+r7));
}

// ---------------------------------------------------------------------------
__global__ __launch_bounds__(256) void vq_e2(const float* __restrict__ emb,
                                             float* __restrict__ e2) {
    int k = blockIdx.x * blockDim.x + threadIdx.x;
    float ek[DD];
    const float4* p = reinterpret_cast<const float4*>(emb + (size_t)k * DD);
#pragma unroll
    for (int q = 0; q < 16; ++q) {
        float4 v = p[q];
        ek[4*q+0]=v.x; ek[4*q+1]=v.y; ek[4*q+2]=v.z; ek[4*q+3]=v.w;
    }
    e2[k] = np_sumsq64(ek);
}

// ---------------------------------------------------------------------------
// B-fragments of the hi/lo bf16 split of emb^T (slot=ct*2+ks; see vq_main).
__global__ __launch_bounds__(256) void vq_bfrag(const float* __restrict__ emb,
                                                short* __restrict__ ebh,
                                                short* __restrict__ ebl) {
    int t    = blockIdx.x * 256 + threadIdx.x;   // 8192 = 128 slots * 64 lanes
    int l    = t & 63;
    int slot = t >> 6;
    int ct = slot >> 1, ks = slot & 1;
    int code  = ct*16 + (l & 15);
    int dbase = ks*32 + (l >> 4)*8;
    const float* ep = emb + (size_t)code*DD + dbase;
    short8v h, lo;
#pragma unroll
    for (int j = 0; j < 8; ++j) {
        float v = ep[j];
        unsigned short hh = bf16_rne(v);
        h[j]  = (short)hh;
        lo[j] = (short)bf16_rne(v - bf16_tof(hh));
    }
    ((short8v*)ebh)[t] = h;
    ((short8v*)ebl)[t] = lo;
}

// ---------------------------------------------------------------------------
// Main (fused): 128 px/block x 1024 codes via bf16 MFMA (3-pass hi/lo),
// TOP-3 + band, in-kernel 2-candidate exact resolve, register dbuf of
// B-frags, FUSED epilogue (z_q + idx-float + fp64 loss partial from LDS).
// 128px -> zsh ~32KB -> 4 blocks/CU (round-14: 64KB -> 2 blk/CU, Occ 21.7%).
__global__ __launch_bounds__(256) void vq_main(
        const float* __restrict__ z, const float* __restrict__ emb,
        const short* __restrict__ ebh, const short* __restrict__ ebl,
        const float* __restrict__ e2,
        int* __restrict__ idx, int* __restrict__ list, int* __restrict__ cnt,
        float* __restrict__ zrows, int zcap,
        float* __restrict__ out, double* __restrict__ partial) {
    __shared__ float zsh[DD * ZSTR];     // ~32.25 KB, [d][px] stride 129
    __shared__ int   idx_loc[PXB];
    __shared__ int   flpx[128], flslot[128];
    __shared__ int   q_px[128], q_k1[128], q_k2[128];
    __shared__ int   nfl, n2c;
    __shared__ double sred[256];
    const int tid = threadIdx.x;
    const int w   = tid >> 6;
    const int l   = tid & 63;
    const int lr  = l & 15;
    const int lg  = l >> 4;
    const int b   = blockIdx.x >> 5;          // 32 blocks per image
    const int hw0 = (blockIdx.x & 31) * PXB;
    const float* zb = z + (size_t)b*(DD*HWSZ) + hw0;

    if (tid == 0) { nfl = 0; n2c = 0; }
    {   // coalesced stage: 2 d-rows per iteration (256 thr = 2 x 128 px)
        const int row = tid >> 7, col = tid & 127;
#pragma unroll 8
        for (int d0 = 0; d0 < DD; d0 += 2)
            zsh[(d0+row)*ZSTR + col] = zb[(size_t)(d0+row)*HWSZ + col];
    }
    __syncthreads();

    // A-frags from LDS. ah/al[rt][ks]; elem j <-> d = ks*32+lg*8+j.
    short8v ah[2][2], al[2][2];
#pragma unroll
    for (int rt = 0; rt < 2; ++rt) {
#pragma unroll
        for (int ks = 0; ks < 2; ++ks) {
            int px = w*32 + rt*16 + lr;
            int dbase = ks*32 + lg*8;
#pragma unroll
            for (int j = 0; j < 8; ++j) {
                float v = zsh[(dbase + j)*ZSTR + px];
                unsigned short hh = bf16_rne(v);
                ah[rt][ks][j] = (short)hh;
                al[rt][ks][j] = (short)bf16_rne(v - bf16_tof(hh));
            }
        }
    }

    float b1a[2][4], b2a[2][4], b3a[2][4];
    int   i1a[2][4], i2a[2][4];
#pragma unroll
    for (int rt = 0; rt < 2; ++rt)
#pragma unroll
        for (int r = 0; r < 4; ++r) {
            b1a[rt][r] = 3.4e38f; b2a[rt][r] = 3.4e38f; b3a[rt][r] = 3.4e38f;
            i1a[rt][r] = 0; i2a[rt][r] = 0;
        }

    const short8v* EBH = (const short8v*)ebh;
    const short8v* EBL = (const short8v*)ebl;

    // register double-buffer: frags + e2 for ct=0 loaded up front
    short8v bh0 = EBH[l],  bh1 = EBH[64 + l];
    short8v bl0 = EBL[l],  bl1 = EBL[64 + l];
    float   e2c = e2[lr];

#pragma unroll 1
    for (int ct = 0; ct < 64; ++ct) {
        int ctn = (ct + 1) & 63;             // wraps harmlessly on last iter
        int s0  = ctn*128 + l;
        short8v nh0 = EBH[s0], nh1 = EBH[s0+64];
        short8v nl0 = EBL[s0], nl1 = EBL[s0+64];
        float   ne2 = e2[ctn*16 + lr];

        int kcol = ct*16 + lr;
#pragma unroll
        for (int rt = 0; rt < 2; ++rt) {
            float4v acc = {0.f, 0.f, 0.f, 0.f};
            acc = __builtin_amdgcn_mfma_f32_16x16x32_bf16(ah[rt][0], bh0, acc, 0,0,0);
            acc = __builtin_amdgcn_mfma_f32_16x16x32_bf16(ah[rt][1], bh1, acc, 0,0,0);
            acc = __builtin_amdgcn_mfma_f32_16x16x32_bf16(ah[rt][0], bl0, acc, 0,0,0);
            acc = __builtin_amdgcn_mfma_f32_16x16x32_bf16(ah[rt][1], bl1, acc, 0,0,0);
            acc = __builtin_amdgcn_mfma_f32_16x16x32_bf16(al[rt][0], bh0, acc, 0,0,0);
            acc = __builtin_amdgcn_mfma_f32_16x16x32_bf16(al[rt][1], bh1, acc, 0,0,0);
#pragma unroll
            for (int r = 0; r < 4; ++r) {
                float s = __builtin_fmaf(-2.f, acc[r], e2c);
                bool lt1 = s < b1a[rt][r];
                bool lt2 = !lt1 && (s < b2a[rt][r]);
                bool lt3 = !lt1 && !lt2 && (s < b3a[rt][r]);
                b3a[rt][r] = (lt1 | lt2) ? b2a[rt][r] : (lt3 ? s : b3a[rt][r]);
                b2a[rt][r] = lt1 ? b1a[rt][r] : (lt2 ? s : b2a[rt][r]);
                i2a[rt][r] = lt1 ? i1a[rt][r] : (lt2 ? kcol : i2a[rt][r]);
                b1a[rt][r] = lt1 ? s : b1a[rt][r];
                i1a[rt][r] = lt1 ? kcol : i1a[rt][r];
            }
        }
        bh0 = nh0; bh1 = nh1; bl0 = nl0; bl1 = nl1; e2c = ne2;
    }

#pragma unroll
    for (int rt = 0; rt < 2; ++rt) {
#pragma unroll
        for (int r = 0; r < 4; ++r) {
            float b1 = b1a[rt][r], b2 = b2a[rt][r], b3 = b3a[rt][r];
            int   i1 = i1a[rt][r], i2 = i2a[rt][r];
#pragma unroll
            for (int m = 1; m < 16; m <<= 1) {       // sorted top-3 merge
                float o1 = __shfl_xor(b1, m, 64);
                float o2 = __shfl_xor(b2, m, 64);
                float o3 = __shfl_xor(b3, m, 64);
                int   oi1 = __shfl_xor(i1, m, 64);
                int   oi2 = __shfl_xor(i2, m, 64);
                bool take = (o1 < b1) || (o1 == b1 && oi1 < i1);
                float w1 = take?o1:b1;  int wi1 = take?oi1:i1;
                float l1 = take?b1:o1;  int li1 = take?i1:oi1;
                float w2 = take?o2:b2;  int wi2 = take?oi2:i2;
                float w3 = take?o3:b3;
                float l2 = take?b2:o2;
                bool t2 = (l1 < w2) || (l1 == w2 && li1 < wi2);
                float n2 = t2 ? l1 : w2;  int ni2 = t2 ? li1 : wi2;
                float n3 = fminf(fminf(fmaxf(w2, l1), w3), l2);
                b1 = w1; i1 = wi1; b2 = n2; i2 = ni2; b3 = n3;
            }
            if (lr == 0) {
                int pxl = w*32 + rt*16 + lg*4 + r;         // local pixel
                int n   = b*HWSZ + hw0 + pxl;
                idx[n] = i1;
                idx_loc[pxl] = i1;
                if (b2 - b1 <= BAND) {
                    if (b3 - b1 <= BAND) {                 // 3+ in band: full
                        int p = atomicAdd(cnt, 1);
                        list[p] = n;
                        int j = atomicAdd(&nfl, 1);
                        flpx[j] = pxl; flslot[j] = p;
                    } else {                               // exactly {i1,i2}
                        int j = atomicAdd(&n2c, 1);
                        q_px[j] = pxl; q_k1[j] = i1; q_k2[j] = i2;
                    }
                }
            }
        }
    }

    __syncthreads();
    // ---- 2-candidate exact resolve (ref fp32 bits), one thread per row ----
    if (tid < n2c) {
        int px = q_px[tid], k1 = q_k1[tid], k2 = q_k2[tid];
        float z2 = np_sumsq64_str(&zsh[px], ZSTR);
        const float* ep1 = emb + (size_t)k1 * DD;
        const float* ep2 = emb + (size_t)k2 * DD;
        float s1 = 0.f, s2 = 0.f;
#pragma unroll
        for (int d = 0; d < DD; ++d) {                 // d-ascending chains
            float zd = zsh[d*ZSTR + px];
            s1 = __builtin_fmaf(zd, ep1[d], s1);
            s2 = __builtin_fmaf(zd, ep2[d], s2);
        }
        float B1v, B2v;
        {
#pragma clang fp contract(off)
            float A1 = z2 + e2[k1]; B1v = __builtin_fmaf(-2.f, s1, A1);
            float A2 = z2 + e2[k2]; B2v = __builtin_fmaf(-2.f, s2, A2);
        }
        int win = (B1v < B2v) ? k1 : ((B2v < B1v) ? k2 : (k1 < k2 ? k1 : k2));
        idx[b*HWSZ + hw0 + px] = win;
        idx_loc[px] = win;
    }

    // ---- packed z copy for full-exact rows (coalesced) ----
    __syncthreads();
    int nf = nfl;
    for (int j0 = 0; j0 < nf; j0 += 4) {
        int jj = j0 + (tid >> 6);
        if (jj < nf) {
            int slot = flslot[jj];
            if (slot < zcap) {
                int d = tid & 63;
                zrows[(size_t)slot*64 + d] = zsh[d*ZSTR + flpx[jj]];
            }
        }
    }
    __syncthreads();

    // ---- fused epilogue: 2 threads per px (d-halves); z from LDS ----
    {
        const int px = tid & 127;
        const int dh = tid >> 7;              // 0 or 1: d in [dh*32, dh*32+32)
        const int ki = idx_loc[px];
        const float4* ep = reinterpret_cast<const float4*>(
                               emb + (size_t)ki*DD + dh*32);
        float* op = out + (size_t)b*(DD*HWSZ) + (size_t)(dh*32)*HWSZ + hw0 + px;
        float lsum = 0.f;
#pragma unroll
        for (int q = 0; q < 8; ++q) {
            float4 v = ep[q];
            int d = dh*32 + 4*q;
            float z0 = zsh[(d+0)*ZSTR + px];
            float z1 = zsh[(d+1)*ZSTR + px];
            float z2v = zsh[(d+2)*ZSTR + px];
            float z3 = zsh[(d+3)*ZSTR + px];
            op[(size_t)(4*q+0)*HWSZ] = v.x;
            op[(size_t)(4*q+1)*HWSZ] = v.y;
            op[(size_t)(4*q+2)*HWSZ] = v.z;
            op[(size_t)(4*q+3)*HWSZ] = v.w;
            float f0 = v.x - z0, f1 = v.y - z1, f2 = v.z - z2v, f3 = v.w - z3;
            lsum = __builtin_fmaf(f0, f0, lsum);
            lsum = __builtin_fmaf(f1, f1, lsum);
            lsum = __builtin_fmaf(f2, f2, lsum);
            lsum = __builtin_fmaf(f3, f3, lsum);
        }
        if (dh == 0) out[IDX_OUT_OFF + b*HWSZ + hw0 + px] = (float)ki;
        sred[tid] = (double)lsum;
    }
    __syncthreads();
#pragma unroll
    for (int sdown = 128; sdown > 0; sdown >>= 1) {
        if (tid < sdown) sred[tid] += sred[tid + sdown];
        __syncthreads();
    }
    if (tid == 0) partial[blockIdx.x] = sred[0];
}

// ---------------------------------------------------------------------------
// Full exact pass v8: ONE BLOCK per rare flagged row (3+ in band). Computes
// the true ref-fp32 argmin AND patches the fused outputs: z_q row, idx
// float, and an fp64 loss delta (atomicAdd; few rows -> noise ~1e-16).
__global__ __launch_bounds__(256) void vq_exact8(
        const float* __restrict__ z, const float* __restrict__ emb,
        const float* __restrict__ e2, const float* __restrict__ zrows,
        const int* __restrict__ list, const int* __restrict__ cnt,
        int zcap, int* __restrict__ idx, float* __restrict__ out,
        double* __restrict__ delta) {
    __shared__ float zsh[DD];
    __shared__ float rbv[256];
    __shared__ int   rbi[256];
    __shared__ double dred[64];
    const int tid = threadIdx.x;
    const int C   = *cnt;

    for (int i = blockIdx.x; i < C; i += gridDim.x) {
        const int n = list[i];
        if (tid < 64) {
            if (i < zcap) {
                zsh[tid] = zrows[(size_t)i*64 + tid];      // coalesced line
            } else {
                zsh[tid] = z[(size_t)(n>>12)*(DD*HWSZ) + (n&4095)
                             + (size_t)tid*HWSZ];
            }
        }
        __syncthreads();

        const float z2 = np_sumsq64_lds(zsh);

        float bestv = 3.4e38f; int bi = 0x7fffffff;
#pragma unroll
        for (int c = 0; c < 4; ++c) {                  // k = tid + c*256, asc
            int k = c*256 + tid;
            const float4* ep = reinterpret_cast<const float4*>(emb + (size_t)k*DD);
            float s = 0.f;
#pragma unroll
            for (int q = 0; q < 16; ++q) {             // d-ascending chain
                float4 v = ep[q];
                s = __builtin_fmaf(zsh[4*q+0], v.x, s);
                s = __builtin_fmaf(zsh[4*q+1], v.y, s);
                s = __builtin_fmaf(zsh[4*q+2], v.z, s);
                s = __builtin_fmaf(zsh[4*q+3], v.w, s);
            }
            float Bv;
            {
#pragma clang fp contract(off)
                float A = z2 + e2[k];
                Bv = __builtin_fmaf(-2.f, s, A);
            }
            if (Bv < bestv) { bestv = Bv; bi = k; }    // first-min (k asc)
        }

        rbv[tid] = bestv; rbi[tid] = bi;
        __syncthreads();
#pragma unroll
        for (int sdown = 128; sdown > 0; sdown >>= 1) {
            if (tid < sdown) {
                float ov = rbv[tid + sdown]; int oi = rbi[tid + sdown];
                if (ov < rbv[tid] || (ov == rbv[tid] && oi < rbi[tid])) {
                    rbv[tid] = ov; rbi[tid] = oi;
                }
            }
            __syncthreads();
        }
        const int win = rbi[0];
        const int old = idx[n];
        if (win != old) {                               // block-uniform branch
            const int bq = n >> 12, hw = n & 4095;
            if (tid < 64) {
                float zd = zsh[tid];
                float en = emb[(size_t)win*DD + tid];
                float eo = emb[(size_t)old*DD + tid];
                out[(size_t)bq*(DD*HWSZ) + (size_t)tid*HWSZ + hw] = en;
                float dn = en - zd, dl = eo - zd;
                dred[tid] = (double)(dn*dn) - (double)(dl*dl);
            }
            __syncthreads();
            if (tid == 0) {
                double s = 0.0;
                for (int j = 0; j < 64; ++j) s += dred[j];
                atomicAdd(delta, s);
                idx[n] = win;
                out[IDX_OUT_OFF + n] = (float)win;
            }
        }
        __syncthreads();
    }
}

// ---------------------------------------------------------------------------
__global__ __launch_bounds__(256) void vq_finalize(
        const double* __restrict__ part, const double* __restrict__ delta,
        float* __restrict__ out) {
    __shared__ double sred[256];
    int t = threadIdx.x;
    sred[t] = part[t] + part[t + 256] + part[t + 512] + part[t + 768];
    __syncthreads();
#pragma unroll
    for (int sdown = 128; sdown > 0; sdown >>= 1) {
        if (t < sdown) sred[t] += sred[t + sdown];
        __syncthreads();
    }
    if (t == 0) {
        double m = (sred[0] + *delta) / (double)NELEM;
        out[LOSS_OFF]     = (float)m;
        out[LOSS_OFF + 1] = (float)(0.25 * m);
    }
}

// ---------------------------------------------------------------------------
extern "C" void kernel_launch(void* const* d_in, const int* in_sizes, int n_in,
                              void* d_out, int out_size, void* d_ws, size_t ws_size,
                              hipStream_t stream) {
    const float* z   = (const float*)d_in[0];
    const float* emb = (const float*)d_in[1];
    float* out = (float*)d_out;
    char*  ws  = (char*)d_ws;

    float*  e2p   = (float*)(ws + WS_E2);
    short*  ebh   = (short*)(ws + WS_EBH);
    short*  ebl   = (short*)(ws + WS_EBL);
    int*    idxp  = (int*)(ws + WS_IDX);
    int*    lst   = (int*)(ws + WS_LIST);
    int*    cntp  = (int*)(ws + WS_CNT);
    double* delta = (double*)(ws + WS_CNT + 8);
    double* part  = (double*)(ws + WS_PART);
    float*  zrows = (float*)(ws + WS_ZROWS);

    long long zrem = (long long)ws_size - (long long)WS_ZROWS;
    int zcap = zrem > 0 ? (int)(zrem / 256) : 0;
    if (zcap > NPIX) zcap = NPIX;

    hipMemsetAsync(cntp, 0, 16, stream);     // cnt + loss delta
    vq_e2       <<<KK/256,   256, 0, stream>>>(emb, e2p);
    vq_bfrag    <<<32,       256, 0, stream>>>(emb, ebh, ebl);
    vq_main     <<<NPIX/PXB, 256, 0, stream>>>(z, emb, ebh, ebl, e2p, idxp,
                                               lst, cntp, zrows, zcap,
                                               out, part);
    vq_exact8   <<<512,      256, 0, stream>>>(z, emb, e2p, zrows, lst, cntp,
                                               zcap, idxp, out, delta);
    vq_finalize <<<1,        256, 0, stream>>>(part, delta, out);
}

// Round 16
// 133.157 us; speedup vs baseline: 3.3131x; 1.0123x over previous
//
#include <hip/hip_runtime.h>

// Problem geometry (fixed by setup_inputs)
#define BB 32
#define DD 64
#define HWSZ 4096                  // H*W
#define KK 1024
#define NPIX (BB*HWSZ)             // 131072
#define NELEM (NPIX*DD)            // 8388608

// Output layout (concatenated float32)
#define IDX_OUT_OFF NELEM
#define LOSS_OFF (IDX_OUT_OFF + NPIX)

// Workspace layout (bytes)
#define WS_E2    0                        // 4 KB
#define WS_EBH   4096                     // 128 KB  B-frags hi
#define WS_EBL   (WS_EBH + KK*DD*2)       // 128 KB  B-frags lo
#define WS_IDX   (WS_EBL + KK*DD*2)       // 512 KB
#define WS_LIST  (WS_IDX + NPIX*4)        // 512 KB
#define WS_CNT   (WS_LIST + NPIX*4)       // 64 B: cnt@+0, loss-delta double@+8
#define WS_PART  (WS_CNT + 64)            // 8 KB (1024 doubles)
#define WS_ZROWS (WS_PART + 8192)         // packed z rows (full-exact rows)

#define PXB 128
#define ZSTR 129                   // zsh row stride (pad: bank-conflict free-ish)

// Ambiguity band. Fast-vs-ref pairwise error <= ~2e-5; low-10-bit k-packing
// adds <= 2*1024*ulp(|s|) ~ 3e-5 worst-case. BAND = 2e-4 keeps ~4x margin.
#define BAND 2e-4f

typedef __attribute__((ext_vector_type(8))) short short8v;
typedef __attribute__((ext_vector_type(4))) float float4v;

__device__ __forceinline__ unsigned short bf16_rne(float f) {
    unsigned u = __float_as_uint(f);
    u += 0x7fffu + ((u >> 16) & 1u);
    return (unsigned short)(u >> 16);
}
__device__ __forceinline__ float bf16_tof(unsigned short h) {
    return __uint_as_float(((unsigned)h) << 16);
}

// numpy-style fp32 sum of 64 squares (squares rounded separately; no FMA).
__device__ __forceinline__ float np_sumsq64(const float* a) {
#pragma clang fp contract(off)
    float r0=0.f,r1=0.f,r2=0.f,r3=0.f,r4=0.f,r5=0.f,r6=0.f,r7=0.f;
#pragma unroll
    for (int i = 0; i < 64; i += 8) {
        r0 += a[i+0]*a[i+0]; r1 += a[i+1]*a[i+1];
        r2 += a[i+2]*a[i+2]; r3 += a[i+3]*a[i+3];
        r4 += a[i+4]*a[i+4]; r5 += a[i+5]*a[i+5];
        r6 += a[i+6]*a[i+6]; r7 += a[i+7]*a[i+7];
    }
    return ((r0+r1)+(r2+r3))+((r4+r5)+(r6+r7));
}

// Same bits, LDS source, sequential addresses.
__device__ __forceinline__ float np_sumsq64_lds(const float* sh) {
#pragma clang fp contract(off)
    float r0=0.f,r1=0.f,r2=0.f,r3=0.f,r4=0.f,r5=0.f,r6=0.f,r7=0.f;
#pragma unroll
    for (int i = 0; i < 64; i += 8) {
        float a0=sh[i+0],a1=sh[i+1],a2=sh[i+2],a3=sh[i+3];
        float a4=sh[i+4],a5=sh[i+5],a6=sh[i+6],a7=sh[i+7];
        r0 += a0*a0; r1 += a1*a1; r2 += a2*a2; r3 += a3*a3;
        r4 += a4*a4; r5 += a5*a5; r6 += a6*a6; r7 += a7*a7;
    }
    return ((r0+r1)+(r2+r3))+((r4+r5)+(r6+r7));
}

// Same bits, LDS source with element stride (column of [d][px] tile).
__device__ __forceinline__ float np_sumsq64_str(const float* sh, int stride) {
#pragma clang fp contract(off)
    float r0=0.f,r1=0.f,r2=0.f,r3=0.f,r4=0.f,r5=0.f,r6=0.f,r7=0.f;
#pragma unroll
    for (int i = 0; i < 64; i += 8) {
        float a0=sh[(i+0)*stride],a1=sh[(i+1)*stride];
        float a2=sh[(i+2)*stride],a3=sh[(i+3)*stride];
        float a4=sh[(i+4)*stride],a5=sh[(i+5)*stride];
        float a6=sh[(i+6)*stride],a7=sh[(i+7)*stride];
        r0 += a0*a0; r1 += a1*a1; r2 += a2*a2; r3 += a3*a3;
        r4 += a4*a4; r5 += a5*a5; r6 += a6*a6; r7 += a7*a7;
    }
    return ((r0+r1)+(r2+r3))+((r4+r5)+(r6+r7));
}

// ---------------------------------------------------------------------------
__global__ __launch_bounds__(256) void vq_e2(const float* __restrict__ emb,
                                             float* __restrict__ e2) {
    int k = blockIdx.x * blockDim.x + threadIdx.x;
    float ek[DD];
    const float4* p = reinterpret_cast<const float4*>(emb + (size_t)k * DD);
#pragma unroll
    for (int q = 0; q < 16; ++q) {
        float4 v = p[q];
        ek[4*q+0]=v.x; ek[4*q+1]=v.y; ek[4*q+2]=v.z; ek[4*q+3]=v.w;
    }
    e2[k] = np_sumsq64(ek);
}

// ---------------------------------------------------------------------------
// B-fragments of the hi/lo bf16 split of emb^T (slot=ct*2+ks; see vq_main).
__global__ __launch_bounds__(256) void vq_bfrag(const float* __restrict__ emb,
                                                short* __restrict__ ebh,
                                                short* __restrict__ ebl) {
    int t    = blockIdx.x * 256 + threadIdx.x;   // 8192 = 128 slots * 64 lanes
    int l    = t & 63;
    int slot = t >> 6;
    int ct = slot >> 1, ks = slot & 1;
    int code  = ct*16 + (l & 15);
    int dbase = ks*32 + (l >> 4)*8;
    const float* ep = emb + (size_t)code*DD + dbase;
    short8v h, lo;
#pragma unroll
    for (int j = 0; j < 8; ++j) {
        float v = ep[j];
        unsigned short hh = bf16_rne(v);
        h[j]  = (short)hh;
        lo[j] = (short)bf16_rne(v - bf16_tof(hh));
    }
    ((short8v*)ebh)[t] = h;
    ((short8v*)ebl)[t] = lo;
}

// ---------------------------------------------------------------------------
// Main (fused): 128 px/block x 1024 codes via bf16 MFMA (3-pass hi/lo).
// TOP-3 via PACKED-FLOAT keys: index embedded in the low 10 mantissa bits
// (k for s>=0, k^1023 for s<0) -> monotone lexicographic (score, first-min-k)
// ordering; top-3 insert is 5 min/max ops, NO index registers, merge has no
// tie logic (keys unique per k). Round-15 counters: bookkeeping was 3x MFMA.
__global__ __launch_bounds__(256) void vq_main(
        const float* __restrict__ z, const float* __restrict__ emb,
        const short* __restrict__ ebh, const short* __restrict__ ebl,
        const float* __restrict__ e2,
        int* __restrict__ idx, int* __restrict__ list, int* __restrict__ cnt,
        float* __restrict__ zrows, int zcap,
        float* __restrict__ out, double* __restrict__ partial) {
    __shared__ float zsh[DD * ZSTR];     // ~32.25 KB, [d][px] stride 129
    __shared__ int   idx_loc[PXB];
    __shared__ int   flpx[128], flslot[128];
    __shared__ int   q_px[128], q_k1[128], q_k2[128];
    __shared__ int   nfl, n2c;
    __shared__ double sred[256];
    const int tid = threadIdx.x;
    const int w   = tid >> 6;
    const int l   = tid & 63;
    const int lr  = l & 15;
    const int lg  = l >> 4;
    const int b   = blockIdx.x >> 5;          // 32 blocks per image
    const int hw0 = (blockIdx.x & 31) * PXB;
    const float* zb = z + (size_t)b*(DD*HWSZ) + hw0;

    if (tid == 0) { nfl = 0; n2c = 0; }
    {   // coalesced stage: 2 d-rows per iteration (256 thr = 2 x 128 px)
        const int row = tid >> 7, col = tid & 127;
#pragma unroll 8
        for (int d0 = 0; d0 < DD; d0 += 2)
            zsh[(d0+row)*ZSTR + col] = zb[(size_t)(d0+row)*HWSZ + col];
    }
    __syncthreads();

    // A-frags from LDS. ah/al[rt][ks]; elem j <-> d = ks*32+lg*8+j.
    short8v ah[2][2], al[2][2];
#pragma unroll
    for (int rt = 0; rt < 2; ++rt) {
#pragma unroll
        for (int ks = 0; ks < 2; ++ks) {
            int px = w*32 + rt*16 + lr;
            int dbase = ks*32 + lg*8;
#pragma unroll
            for (int j = 0; j < 8; ++j) {
                float v = zsh[(dbase + j)*ZSTR + px];
                unsigned short hh = bf16_rne(v);
                ah[rt][ks][j] = (short)hh;
                al[rt][ks][j] = (short)bf16_rne(v - bf16_tof(hh));
            }
        }
    }

    // packed top-3 keys only (no index arrays)
    float b1a[2][4], b2a[2][4], b3a[2][4];
#pragma unroll
    for (int rt = 0; rt < 2; ++rt)
#pragma unroll
        for (int r = 0; r < 4; ++r) {
            b1a[rt][r] = 3.4e38f; b2a[rt][r] = 3.4e38f; b3a[rt][r] = 3.4e38f;
        }

    const short8v* EBH = (const short8v*)ebh;
    const short8v* EBL = (const short8v*)ebl;

    // register double-buffer: frags + e2 for ct=0 loaded up front
    short8v bh0 = EBH[l],  bh1 = EBH[64 + l];
    short8v bl0 = EBL[l],  bl1 = EBL[64 + l];
    float   e2c = e2[lr];

#pragma unroll 1
    for (int ct = 0; ct < 64; ++ct) {
        int ctn = (ct + 1) & 63;             // wraps harmlessly on last iter
        int s0  = ctn*128 + l;
        short8v nh0 = EBH[s0], nh1 = EBH[s0+64];
        short8v nl0 = EBL[s0], nl1 = EBL[s0+64];
        float   ne2 = e2[ctn*16 + lr];

        const unsigned kf = (unsigned)(ct*16 + lr);     // forward k
        const unsigned kr = kf ^ 1023u;                 // reversed (neg scores)
#pragma unroll
        for (int rt = 0; rt < 2; ++rt) {
            float4v acc = {0.f, 0.f, 0.f, 0.f};
            acc = __builtin_amdgcn_mfma_f32_16x16x32_bf16(ah[rt][0], bh0, acc, 0,0,0);
            acc = __builtin_amdgcn_mfma_f32_16x16x32_bf16(ah[rt][1], bh1, acc, 0,0,0);
            acc = __builtin_amdgcn_mfma_f32_16x16x32_bf16(ah[rt][0], bl0, acc, 0,0,0);
            acc = __builtin_amdgcn_mfma_f32_16x16x32_bf16(ah[rt][1], bl1, acc, 0,0,0);
            acc = __builtin_amdgcn_mfma_f32_16x16x32_bf16(al[rt][0], bh0, acc, 0,0,0);
            acc = __builtin_amdgcn_mfma_f32_16x16x32_bf16(al[rt][1], bh1, acc, 0,0,0);
#pragma unroll
            for (int r = 0; r < 4; ++r) {
                float s = __builtin_fmaf(-2.f, acc[r], e2c);
                unsigned su = __float_as_uint(s) & ~1023u;
                unsigned kk = ((int)su < 0) ? kr : kf;
                float p = __uint_as_float(su | kk);
                float ob2 = b2a[rt][r];
                b3a[rt][r] = fminf(b3a[rt][r], fmaxf(ob2, p));
                b2a[rt][r] = fmaxf(b1a[rt][r], fminf(ob2, p));
                b1a[rt][r] = fminf(b1a[rt][r], p);
            }
        }
        bh0 = nh0; bh1 = nh1; bl0 = nl0; bl1 = nl1; e2c = ne2;
    }

#pragma unroll
    for (int rt = 0; rt < 2; ++rt) {
#pragma unroll
        for (int r = 0; r < 4; ++r) {
            float b1 = b1a[rt][r], b2 = b2a[rt][r], b3 = b3a[rt][r];
#pragma unroll
            for (int m = 1; m < 16; m <<= 1) {   // sorted-triple min-merge
                float o1 = __shfl_xor(b1, m, 64);
                float o2 = __shfl_xor(b2, m, 64);
                float o3 = __shfl_xor(b3, m, 64);
                float mx  = fmaxf(b1, o1);
                float mn2 = fminf(b2, o2);
                float n1 = fminf(b1, o1);
                float n2 = fminf(mx, mn2);
                float n3 = fminf(fminf(fmaxf(mn2, mx), fmaxf(b2, o2)),
                                 fminf(b3, o3));
                b1 = n1; b2 = n2; b3 = n3;
            }
            if (lr == 0) {
                unsigned u1 = __float_as_uint(b1);
                int i1 = (int)(u1 & 1023u); if ((int)u1 < 0) i1 ^= 1023;
                int pxl = w*32 + rt*16 + lg*4 + r;         // local pixel
                int n   = b*HWSZ + hw0 + pxl;
                idx[n] = i1;
                idx_loc[pxl] = i1;
                if (b2 - b1 <= BAND) {
                    if (b3 - b1 <= BAND) {                 // 3+ in band: full
                        int p = atomicAdd(cnt, 1);
                        list[p] = n;
                        int j = atomicAdd(&nfl, 1);
                        flpx[j] = pxl; flslot[j] = p;
                    } else {                               // exactly {i1,i2}
                        unsigned u2 = __float_as_uint(b2);
                        int i2 = (int)(u2 & 1023u); if ((int)u2 < 0) i2 ^= 1023;
                        int j = atomicAdd(&n2c, 1);
                        q_px[j] = pxl; q_k1[j] = i1; q_k2[j] = i2;
                    }
                }
            }
        }
    }

    __syncthreads();
    // ---- 2-candidate exact resolve (ref fp32 bits), one thread per row ----
    if (tid < n2c) {
        int px = q_px[tid], k1 = q_k1[tid], k2 = q_k2[tid];
        float z2 = np_sumsq64_str(&zsh[px], ZSTR);
        const float* ep1 = emb + (size_t)k1 * DD;
        const float* ep2 = emb + (size_t)k2 * DD;
        float s1 = 0.f, s2 = 0.f;
#pragma unroll
        for (int d = 0; d < DD; ++d) {                 // d-ascending chains
            float zd = zsh[d*ZSTR + px];
            s1 = __builtin_fmaf(zd, ep1[d], s1);
            s2 = __builtin_fmaf(zd, ep2[d], s2);
        }
        float B1v, B2v;
        {
#pragma clang fp contract(off)
            float A1 = z2 + e2[k1]; B1v = __builtin_fmaf(-2.f, s1, A1);
            float A2 = z2 + e2[k2]; B2v = __builtin_fmaf(-2.f, s2, A2);
        }
        int win;
        if (k1 < k2) win = (B2v < B1v) ? k2 : k1;      // first-min tie-break
        else         win = (B1v < B2v) ? k1 : k2;
        idx[b*HWSZ + hw0 + px] = win;
        idx_loc[px] = win;
    }

    // ---- packed z copy for full-exact rows (coalesced) ----
    __syncthreads();
    int nf = nfl;
    for (int j0 = 0; j0 < nf; j0 += 4) {
        int jj = j0 + (tid >> 6);
        if (jj < nf) {
            int slot = flslot[jj];
            if (slot < zcap) {
                int d = tid & 63;
                zrows[(size_t)slot*64 + d] = zsh[d*ZSTR + flpx[jj]];
            }
        }
    }
    __syncthreads();

    // ---- fused epilogue: 2 threads per px (d-halves); z from LDS ----
    {
        const int px = tid & 127;
        const int dh = tid >> 7;              // 0 or 1: d in [dh*32, dh*32+32)
        const int ki = idx_loc[px];
        const float4* ep = reinterpret_cast<const float4*>(
                               emb + (size_t)ki*DD + dh*32);
        float* op = out + (size_t)b*(DD*HWSZ) + (size_t)(dh*32)*HWSZ + hw0 + px;
        float lsum = 0.f;
#pragma unroll
        for (int q = 0; q < 8; ++q) {
            float4 v = ep[q];
            int d = dh*32 + 4*q;
            float z0 = zsh[(d+0)*ZSTR + px];
            float z1 = zsh[(d+1)*ZSTR + px];
            float z2v = zsh[(d+2)*ZSTR + px];
            float z3 = zsh[(d+3)*ZSTR + px];
            op[(size_t)(4*q+0)*HWSZ] = v.x;
            op[(size_t)(4*q+1)*HWSZ] = v.y;
            op[(size_t)(4*q+2)*HWSZ] = v.z;
            op[(size_t)(4*q+3)*HWSZ] = v.w;
            float f0 = v.x - z0, f1 = v.y - z1, f2 = v.z - z2v, f3 = v.w - z3;
            lsum = __builtin_fmaf(f0, f0, lsum);
            lsum = __builtin_fmaf(f1, f1, lsum);
            lsum = __builtin_fmaf(f2, f2, lsum);
            lsum = __builtin_fmaf(f3, f3, lsum);
        }
        if (dh == 0) out[IDX_OUT_OFF + b*HWSZ + hw0 + px] = (float)ki;
        sred[tid] = (double)lsum;
    }
    __syncthreads();
#pragma unroll
    for (int sdown = 128; sdown > 0; sdown >>= 1) {
        if (tid < sdown) sred[tid] += sred[tid + sdown];
        __syncthreads();
    }
    if (tid == 0) partial[blockIdx.x] = sred[0];
}

// ---------------------------------------------------------------------------
// Full exact pass v8: ONE BLOCK per rare flagged row (3+ in band). Computes
// the true ref-fp32 argmin AND patches the fused outputs: z_q row, idx
// float, and an fp64 loss delta (atomicAdd; few rows -> noise ~1e-16).
__global__ __launch_bounds__(256) void vq_exact8(
        const float* __restrict__ z, const float* __restrict__ emb,
        const float* __restrict__ e2, const float* __restrict__ zrows,
        const int* __restrict__ list, const int* __restrict__ cnt,
        int zcap, int* __restrict__ idx, float* __restrict__ out,
        double* __restrict__ delta) {
    __shared__ float zsh[DD];
    __shared__ float rbv[256];
    __shared__ int   rbi[256];
    __shared__ double dred[64];
    const int tid = threadIdx.x;
    const int C   = *cnt;

    for (int i = blockIdx.x; i < C; i += gridDim.x) {
        const int n = list[i];
        if (tid < 64) {
            if (i < zcap) {
                zsh[tid] = zrows[(size_t)i*64 + tid];      // coalesced line
            } else {
                zsh[tid] = z[(size_t)(n>>12)*(DD*HWSZ) + (n&4095)
                             + (size_t)tid*HWSZ];
            }
        }
        __syncthreads();

        const float z2 = np_sumsq64_lds(zsh);

        float bestv = 3.4e38f; int bi = 0x7fffffff;
#pragma unroll
        for (int c = 0; c < 4; ++c) {                  // k = tid + c*256, asc
            int k = c*256 + tid;
            const float4* ep = reinterpret_cast<const float4*>(emb + (size_t)k*DD);
            float s = 0.f;
#pragma unroll
            for (int q = 0; q < 16; ++q) {             // d-ascending chain
                float4 v = ep[q];
                s = __builtin_fmaf(zsh[4*q+0], v.x, s);
                s = __builtin_fmaf(zsh[4*q+1], v.y, s);
                s = __builtin_fmaf(zsh[4*q+2], v.z, s);
                s = __builtin_fmaf(zsh[4*q+3], v.w, s);
            }
            float Bv;
            {
#pragma clang fp contract(off)
                float A = z2 + e2[k];
                Bv = __builtin_fmaf(-2.f, s, A);
            }
            if (Bv < bestv) { bestv = Bv; bi = k; }    // first-min (k asc)
        }

        rbv[tid] = bestv; rbi[tid] = bi;
        __syncthreads();
#pragma unroll
        for (int sdown = 128; sdown > 0; sdown >>= 1) {
            if (tid < sdown) {
                float ov = rbv[tid + sdown]; int oi = rbi[tid + sdown];
                if (ov < rbv[tid] || (ov == rbv[tid] && oi < rbi[tid])) {
                    rbv[tid] = ov; rbi[tid] = oi;
                }
            }
            __syncthreads();
        }
        const int win = rbi[0];
        const int old = idx[n];
        if (win != old) {                               // block-uniform branch
            const int bq = n >> 12, hw = n & 4095;
            if (tid < 64) {
                float zd = zsh[tid];
                float en = emb[(size_t)win*DD + tid];
                float eo = emb[(size_t)old*DD + tid];
                out[(size_t)bq*(DD*HWSZ) + (size_t)tid*HWSZ + hw] = en;
                float dn = en - zd, dl = eo - zd;
                dred[tid] = (double)(dn*dn) - (double)(dl*dl);
            }
            __syncthreads();
            if (tid == 0) {
                double s = 0.0;
                for (int j = 0; j < 64; ++j) s += dred[j];
                atomicAdd(delta, s);
                idx[n] = win;
                out[IDX_OUT_OFF + n] = (float)win;
            }
        }
        __syncthreads();
    }
}

// ---------------------------------------------------------------------------
__global__ __launch_bounds__(256) void vq_finalize(
        const double* __restrict__ part, const double* __restrict__ delta,
        float* __restrict__ out) {
    __shared__ double sred[256];
    int t = threadIdx.x;
    sred[t] = part[t] + part[t + 256] + part[t + 512] + part[t + 768];
    __syncthreads();
#pragma unroll
    for (int sdown = 128; sdown > 0; sdown >>= 1) {
        if (t < sdown) sred[t] += sred[t + sdown];
        __syncthreads();
    }
    if (t == 0) {
        double m = (sred[0] + *delta) / (double)NELEM;
        out[LOSS_OFF]     = (float)m;
        out[LOSS_OFF + 1] = (float)(0.25 * m);
    }
}

// ---------------------------------------------------------------------------
extern "C" void kernel_launch(void* const* d_in, const int* in_sizes, int n_in,
                              void* d_out, int out_size, void* d_ws, size_t ws_size,
                              hipStream_t stream) {
    const float* z   = (const float*)d_in[0];
    const float* emb = (const float*)d_in[1];
    float* out = (float*)d_out;
    char*  ws  = (char*)d_ws;

    float*  e2p   = (float*)(ws + WS_E2);
    short*  ebh   = (short*)(ws + WS_EBH);
    short*  ebl   = (short*)(ws + WS_EBL);
    int*    idxp  = (int*)(ws + WS_IDX);
    int*    lst   = (int*)(ws + WS_LIST);
    int*    cntp  = (int*)(ws + WS_CNT);
    double* delta = (double*)(ws + WS_CNT + 8);
    double* part  = (double*)(ws + WS_PART);
    float*  zrows = (float*)(ws + WS_ZROWS);

    long long zrem = (long long)ws_size - (long long)WS_ZROWS;
    int zcap = zrem > 0 ? (int)(zrem / 256) : 0;
    if (zcap > NPIX) zcap = NPIX;

    hipMemsetAsync(cntp, 0, 16, stream);     // cnt + loss delta
    vq_e2       <<<KK/256,   256, 0, stream>>>(emb, e2p);
    vq_bfrag    <<<32,       256, 0, stream>>>(emb, ebh, ebl);
    vq_main     <<<NPIX/PXB, 256, 0, stream>>>(z, emb, ebh, ebl, e2p, idxp,
                                               lst, cntp, zrows, zcap,
                                               out, part);
    vq_exact8   <<<512,      256, 0, stream>>>(z, emb, e2p, zrows, lst, cntp,
                                               zcap, idxp, out, delta);
    vq_finalize <<<1,        256, 0, stream>>>(part, delta, out);
}